// Round 1
// baseline (485.379 us; speedup 1.0000x reference)
//
#include <hip/hip_runtime.h>
#include <hip/hip_bf16.h>

// ---------------------------------------------------------------------------
// LPGCNHyperConvAblation, round 10: MFMA (16x16x32 bf16) GEMMs replace the
// VALU 4x4-microtile GEMMs. 128-row tiles, full-K LDS staging, B^T layout,
// +8-bf16 row pad for bank-conflict-free ds_read_b128. Everything else
// (CSR build, gathers, fused tail) unchanged from round 9.
// ---------------------------------------------------------------------------

typedef __attribute__((ext_vector_type(8))) short s16x8;
typedef __attribute__((ext_vector_type(4))) float f32x4;

__device__ __forceinline__ float ldf(const void* p, int f32, long long i) {
    if (f32) return ((const float*)p)[i];
    unsigned v = ((unsigned)((const unsigned short*)p)[i]) << 16;
    return __uint_as_float(v);
}

__device__ __forceinline__ int ldi(const int* __restrict__ w, int i64, long long i, int lim) {
    int v = i64 ? w[2 * i] : w[i];
    return ((unsigned)v < (unsigned)lim) ? v : 0;
}

__device__ __forceinline__ float b2f(unsigned short u) {
    return __uint_as_float(((unsigned)u) << 16);
}
__device__ __forceinline__ unsigned short f2b(float f) {
    __hip_bfloat16 h = __float2bfloat16(f);
    return *reinterpret_cast<unsigned short*>(&h);
}
__device__ __forceinline__ float4 b2f4(ushort4 u) {
    return make_float4(b2f(u.x), b2f(u.y), b2f(u.z), b2f(u.w));
}
__device__ __forceinline__ ushort4 f2b4(float4 v) {
    ushort4 u; u.x = f2b(v.x); u.y = f2b(v.y); u.z = f2b(v.z); u.w = f2b(v.w);
    return u;
}

// --- fused dtype detection ---------------------------------------------------
struct DPtrs { const void* p[13]; int n[13]; };

__global__ void detect_k(DPtrs dp, int* __restrict__ flags) {
    int b = blockIdx.x;
    __shared__ int cnt;
    if (threadIdx.x == 0) cnt = 0;
    __syncthreads();
    int c = 0;
    if (b < 11) {
        const unsigned short* u = (const unsigned short*)dp.p[b];
        int np = dp.n[b]; if (np > 2048) np = 2048;
        for (int i = threadIdx.x; i < np; i += blockDim.x) {
            unsigned e = (u[i] >> 7) & 0xFFu;
            if (e != 0u && (e < 90u || e > 160u)) c++;
        }
        atomicAdd(&cnt, c);
        __syncthreads();
        if (threadIdx.x == 0) flags[b] = (cnt * 8 > np) ? 1 : 0;
    } else {
        const int* w = (const int*)dp.p[b];
        int np = dp.n[b]; if (np > 1024) np = 1024;
        for (int i = threadIdx.x; i < np; i += blockDim.x)
            if (w[2 * i + 1] != 0) c++;
        atomicAdd(&cnt, c);
        __syncthreads();
        if (threadIdx.x == 0) flags[b] = (cnt == 0) ? 1 : 0;
    }
}

// --- CSR build (atomic-free pipeline) ----------------------------------------
struct Item { int b1; unsigned p1; int b2; unsigned p2; };

__device__ __forceinline__ Item decode(const int* __restrict__ ew, const int* __restrict__ hw,
                                       const int* __restrict__ FL, long long i,
                                       int E, int P, int N, int HE, int shN, int shH) {
    Item it; it.b2 = -1; it.p2 = 0;
    if (i < E) {
        int g = FL[11];
        int key = ldi(ew, g, (long long)E + i, N);
        int val = ldi(ew, g, i, N);
        it.b1 = key >> shN;
        it.p1 = ((unsigned)(key & ((1 << shN) - 1)) << 20) | (unsigned)val;
    } else {
        long long j = i - E;
        int g = FL[12];
        int nd = ldi(hw, g, j, N);
        int he = ldi(hw, g, (long long)P + j, HE);
        it.b1 = 256 + (nd >> shN);
        it.p1 = ((unsigned)(nd & ((1 << shN) - 1)) << 20) | (unsigned)he;
        it.b2 = 512 + (he >> shH);
        it.p2 = ((unsigned)(he & ((1 << shH) - 1)) << 20) | (unsigned)nd;
    }
    return it;
}

__global__ void bucket_count_k(const int* __restrict__ ew, const int* __restrict__ hw,
                               const int* __restrict__ FL, int* __restrict__ gcnt,
                               int E, int P, int N, int HE, int shN, int shH) {
    __shared__ int hist[768];
    int t = threadIdx.x;
    for (int b = t; b < 768; b += 256) hist[b] = 0;
    __syncthreads();
    long long T = (long long)E + P;
    long long stride = (long long)gridDim.x * 256;
    for (long long i = (long long)blockIdx.x * 256 + t; i < T; i += stride) {
        Item it = decode(ew, hw, FL, i, E, P, N, HE, shN, shH);
        atomicAdd(&hist[it.b1], 1);
        if (it.b2 >= 0) atomicAdd(&hist[it.b2], 1);
    }
    __syncthreads();
    for (int b = t; b < 768; b += 256) {
        int h = hist[b];
        if (h) atomicAdd(&gcnt[b], h);
    }
}

__global__ void bucket_scan_k(const int* __restrict__ gcnt, int* __restrict__ bkOff,
                              int* __restrict__ gcur, int E, int P) {
    __shared__ int sh[256];
    int t = threadIdx.x;
    long long rbase[3] = {0, (long long)E, (long long)E + P};
    for (int c = 0; c < 3; c++) {
        int v = gcnt[c * 256 + t];
        sh[t] = v;
        __syncthreads();
        for (int o = 1; o < 256; o <<= 1) {
            int y = (t >= o) ? sh[t - o] : 0;
            __syncthreads();
            sh[t] += y;
            __syncthreads();
        }
        int excl = sh[t] - v;
        bkOff[c * 256 + t] = excl;
        gcur[c * 256 + t] = (int)(rbase[c] + excl);
        __syncthreads();
    }
}

#define PCHUNK 8192

__global__ void bucket_place_k(const int* __restrict__ ew, const int* __restrict__ hw,
                               const int* __restrict__ FL, int* __restrict__ gcur,
                               unsigned* __restrict__ pbuf,
                               int E, int P, int N, int HE, int shN, int shH) {
    __shared__ int hist[768];
    __shared__ int cur[768];
    long long T = (long long)E + P;
    long long start = (long long)blockIdx.x * PCHUNK;
    long long end = start + PCHUNK; if (end > T) end = T;
    int t = threadIdx.x;
    for (int b = t; b < 768; b += 256) hist[b] = 0;
    __syncthreads();
    for (long long i = start + t; i < end; i += 256) {
        Item it = decode(ew, hw, FL, i, E, P, N, HE, shN, shH);
        atomicAdd(&hist[it.b1], 1);
        if (it.b2 >= 0) atomicAdd(&hist[it.b2], 1);
    }
    __syncthreads();
    for (int b = t; b < 768; b += 256) {
        int h = hist[b];
        cur[b] = h ? atomicAdd(&gcur[b], h) : 0;
    }
    __syncthreads();
    for (long long i = start + t; i < end; i += 256) {
        Item it = decode(ew, hw, FL, i, E, P, N, HE, shN, shH);
        int s1 = atomicAdd(&cur[it.b1], 1);
        pbuf[s1] = it.p1;
        if (it.b2 >= 0) {
            int s2 = atomicAdd(&cur[it.b2], 1);
            pbuf[s2] = it.p2;
        }
    }
}

__global__ void build_k(const unsigned* __restrict__ pbuf,
                        const int* __restrict__ gcnt, const int* __restrict__ bkOff,
                        int* __restrict__ eoff, int* __restrict__ ecnt, int* __restrict__ esrc,
                        int* __restrict__ poffN, int* __restrict__ pcntN, int* __restrict__ pheL,
                        int* __restrict__ poffH, int* __restrict__ pcntH, int* __restrict__ pniL,
                        int E, int P, int N, int HE, int shN, int shH) {
    __shared__ int hist[512];
    __shared__ int offs[512];
    __shared__ int s2[256];
    int b = blockIdx.x, t = threadIdx.x;
    int csr = b >> 8, lb = b & 255;
    int sh    = (csr == 2) ? shH : shN;
    int nkeys = (csr == 2) ? HE : N;
    int span = 1 << sh;
    int keyBase = lb << sh;
    if (keyBase >= nkeys) return;
    int keyEnd = keyBase + span; if (keyEnd > nkeys) keyEnd = nkeys;
    int cnt = gcnt[b];
    long long rbase = (csr == 0) ? 0 : ((csr == 1) ? (long long)E : (long long)E + P);
    long long pstart = rbase + bkOff[b];
    int lstBase = bkOff[b];
    int* off  = (csr == 0) ? eoff : ((csr == 1) ? poffN : poffH);
    int* cntA = (csr == 0) ? ecnt : ((csr == 1) ? pcntN : pcntH);
    int* lst  = (csr == 0) ? esrc : ((csr == 1) ? pheL : pniL);

    for (int k = t; k < 512; k += 256) hist[k] = 0;
    __syncthreads();
    for (int i = t; i < cnt; i += 256)
        atomicAdd(&hist[pbuf[pstart + i] >> 20], 1);
    __syncthreads();
    int a0 = hist[2 * t], a1 = hist[2 * t + 1];
    s2[t] = a0 + a1;
    __syncthreads();
    for (int o = 1; o < 256; o <<= 1) {
        int y = (t >= o) ? s2[t - o] : 0;
        __syncthreads();
        s2[t] += y;
        __syncthreads();
    }
    int excl = s2[t] - (a0 + a1);
    offs[2 * t] = excl;
    offs[2 * t + 1] = excl + a0;
    __syncthreads();
    for (int k = keyBase + t; k < keyEnd; k += 256) {
        off[k]  = lstBase + offs[k - keyBase];
        cntA[k] = hist[k - keyBase];
    }
    __syncthreads();
    for (int i = t; i < cnt; i += 256) {
        unsigned u = pbuf[pstart + i];
        int lk = u >> 20;
        int slot = atomicAdd(&offs[lk], 1);
        lst[lstBase + slot] = (int)(u & 0xFFFFFu);
    }
}

// --- fused norm factors ------------------------------------------------------
__global__ void norms_k(const int* __restrict__ ecnt, const int* __restrict__ pcntN,
                        const int* __restrict__ pcntH, float* __restrict__ dis,
                        float* __restrict__ Dinv, float* __restrict__ Binv, int N, int HE) {
    int i = blockIdx.x * blockDim.x + threadIdx.x;
    if (i < N) dis[i] = rsqrtf((float)(ecnt[i] + 1));
    else if (i < 2 * N) { int c = pcntN[i - N]; Dinv[i - N] = c ? (1.f / (float)c) : 0.f; }
    else if (i < 2 * N + HE) { int c = pcntH[i - 2 * N]; Binv[i - 2 * N] = c ? (1.f / (float)c) : 0.f; }
}

// --- Wlp2 = W_c2 @ W_lp, bias2 = b_c2 @ W_lp + b_lp  (LDS-staged) ------------
__global__ void wlp2_k(const void* Wc2, const int* fWc2, const void* Wlp, const int* fWlp,
                       const void* bc2, const int* fbc2, const void* blp, const int* fblp,
                       float* __restrict__ Wlp2, float* __restrict__ bias2, int NC) {
    extern __shared__ float sm[];
    float* sW2 = sm;                 // 64*NC  (W_c2)
    float* sLP = sm + 64 * NC;       // NC*NC  (W_lp)
    int t = threadIdx.x;
    int fw2 = fWc2[0], flp = fWlp[0];
    for (int e = t; e < 64 * NC; e += blockDim.x) sW2[e] = ldf(Wc2, fw2, e);
    for (int e = t; e < NC * NC; e += blockDim.x) sLP[e] = ldf(Wlp, flp, e);
    __syncthreads();
    for (int e = t; e < 64 * NC; e += blockDim.x) {
        int r = e / NC, c = e % NC;
        float s = 0.f;
        for (int k = 0; k < NC; k++) s = fmaf(sW2[r * NC + k], sLP[k * NC + c], s);
        Wlp2[e] = s;
    }
    if (t < NC) {
        float s = ldf(blp, fblp[0], t);
        int fb2 = fbc2[0];
        for (int k = 0; k < NC; k++) s = fmaf(ldf(bc2, fb2, k), sLP[k * NC + t], s);
        bias2[t] = s;
    }
}

// --- bf16 gathers: 4 rows/wave, 16 lanes x ushort4 (D=64) --------------------
__global__ void gat_n2e_k(const ushort4* __restrict__ xw, const int* __restrict__ off,
                          const int* __restrict__ cnt, const int* __restrict__ lst,
                          const float* __restrict__ Binv, ushort4* __restrict__ ef, int HE) {
    int idx = blockIdx.x * blockDim.x + threadIdx.x;
    int e = idx >> 4, l = idx & 15;
    if (e >= HE) return;
    int o = off[e], c = cnt[e];
    float4 a = make_float4(0.f, 0.f, 0.f, 0.f);
    int j = 0;
    for (; j + 4 <= c; j += 4) {
        int s0 = lst[o + j], s1 = lst[o + j + 1], s2 = lst[o + j + 2], s3 = lst[o + j + 3];
        float4 v0 = b2f4(xw[((long long)s0 << 4) + l]);
        float4 v1 = b2f4(xw[((long long)s1 << 4) + l]);
        float4 v2 = b2f4(xw[((long long)s2 << 4) + l]);
        float4 v3 = b2f4(xw[((long long)s3 << 4) + l]);
        a.x += (v0.x + v1.x) + (v2.x + v3.x);
        a.y += (v0.y + v1.y) + (v2.y + v3.y);
        a.z += (v0.z + v1.z) + (v2.z + v3.z);
        a.w += (v0.w + v1.w) + (v2.w + v3.w);
    }
    for (; j < c; j++) {
        float4 v = b2f4(xw[((long long)lst[o + j] << 4) + l]);
        a.x += v.x; a.y += v.y; a.z += v.z; a.w += v.w;
    }
    float bi = Binv[e];
    a.x *= bi; a.y *= bi; a.z *= bi; a.w *= bi;
    ef[((long long)e << 4) + l] = f2b4(a);
}

// hyperedge -> node: out = Dinv*sum + bias (+relu), bf16 out
template <bool RELU>
__global__ void gat_e2n_k(const ushort4* __restrict__ ef, const int* __restrict__ off,
                          const int* __restrict__ cnt, const int* __restrict__ lst,
                          const float* __restrict__ Dinv, const void* __restrict__ bias,
                          const int* __restrict__ fb, ushort4* __restrict__ out, int N) {
    int idx = blockIdx.x * blockDim.x + threadIdx.x;
    int w = idx >> 4, l = idx & 15;
    if (w >= N) return;
    int o = off[w], c = cnt[w];
    float4 a = make_float4(0.f, 0.f, 0.f, 0.f);
    int j = 0;
    for (; j + 4 <= c; j += 4) {
        int s0 = lst[o + j], s1 = lst[o + j + 1], s2 = lst[o + j + 2], s3 = lst[o + j + 3];
        float4 v0 = b2f4(ef[((long long)s0 << 4) + l]);
        float4 v1 = b2f4(ef[((long long)s1 << 4) + l]);
        float4 v2 = b2f4(ef[((long long)s2 << 4) + l]);
        float4 v3 = b2f4(ef[((long long)s3 << 4) + l]);
        a.x += (v0.x + v1.x) + (v2.x + v3.x);
        a.y += (v0.y + v1.y) + (v2.y + v3.y);
        a.z += (v0.z + v1.z) + (v2.z + v3.z);
        a.w += (v0.w + v1.w) + (v2.w + v3.w);
    }
    for (; j < c; j++) {
        float4 v = b2f4(ef[((long long)lst[o + j] << 4) + l]);
        a.x += v.x; a.y += v.y; a.z += v.z; a.w += v.w;
    }
    float di = Dinv[w];
    int fbv = fb[0];
    float4 b = make_float4(ldf(bias, fbv, 4 * l), ldf(bias, fbv, 4 * l + 1),
                           ldf(bias, fbv, 4 * l + 2), ldf(bias, fbv, 4 * l + 3));
    a.x = a.x * di + b.x; a.y = a.y * di + b.y;
    a.z = a.z * di + b.z; a.w = a.w * di + b.w;
    if (RELU) {
        a.x = fmaxf(a.x, 0.f); a.y = fmaxf(a.y, 0.f);
        a.z = fmaxf(a.z, 0.f); a.w = fmaxf(a.w, 0.f);
    }
    out[((long long)w << 4) + l] = f2b4(a);
}

// GCN aggregation on pre-scaled bf16 y, bf16 out
template <bool RELU>
__global__ void gcn_gat_k(const ushort4* __restrict__ y, const int* __restrict__ off,
                          const int* __restrict__ cnt, const int* __restrict__ lst,
                          const float* __restrict__ dis, const void* __restrict__ bias,
                          const int* __restrict__ fb, ushort4* __restrict__ out, int N) {
    int idx = blockIdx.x * blockDim.x + threadIdx.x;
    int w = idx >> 4, l = idx & 15;
    if (w >= N) return;
    int o = off[w], c = cnt[w];
    float4 a = b2f4(y[((long long)w << 4) + l]);
    int j = 0;
    for (; j + 4 <= c; j += 4) {
        int s0 = lst[o + j], s1 = lst[o + j + 1], s2 = lst[o + j + 2], s3 = lst[o + j + 3];
        float4 v0 = b2f4(y[((long long)s0 << 4) + l]);
        float4 v1 = b2f4(y[((long long)s1 << 4) + l]);
        float4 v2 = b2f4(y[((long long)s2 << 4) + l]);
        float4 v3 = b2f4(y[((long long)s3 << 4) + l]);
        a.x += (v0.x + v1.x) + (v2.x + v3.x);
        a.y += (v0.y + v1.y) + (v2.y + v3.y);
        a.z += (v0.z + v1.z) + (v2.z + v3.z);
        a.w += (v0.w + v1.w) + (v2.w + v3.w);
    }
    for (; j < c; j++) {
        float4 v = b2f4(y[((long long)lst[o + j] << 4) + l]);
        a.x += v.x; a.y += v.y; a.z += v.z; a.w += v.w;
    }
    float dd = dis[w];
    int fbv = fb[0];
    float4 b = make_float4(ldf(bias, fbv, 4 * l), ldf(bias, fbv, 4 * l + 1),
                           ldf(bias, fbv, 4 * l + 2), ldf(bias, fbv, 4 * l + 3));
    a.x = a.x * dd + b.x; a.y = a.y * dd + b.y;
    a.z = a.z * dd + b.z; a.w = a.w * dd + b.w;
    if (RELU) {
        a.x = fmaxf(a.x, 0.f); a.y = fmaxf(a.y, 0.f);
        a.z = fmaxf(a.z, 0.f); a.w = fmaxf(a.w, 0.f);
    }
    out[((long long)w << 4) + l] = f2b4(a);
}

// final GCN aggregation over bf16 y2 (M=NC), writes d_out fp32
__global__ void gcn_gatM_k(const ushort4* __restrict__ y2, const int* __restrict__ off,
                           const int* __restrict__ cnt, const int* __restrict__ lst,
                           const float* __restrict__ dis, const float* __restrict__ bias2,
                           float4* __restrict__ out4, int N, int nc4, int npw) {
    int idx = blockIdx.x * blockDim.x + threadIdx.x;
    int wave = idx >> 6, l64 = idx & 63;
    int grp = l64 / 10, li = l64 - grp * 10;
    if (nc4 != 10) { grp = l64 / nc4; li = l64 - grp * nc4; }
    int w = wave * npw + grp;
    if (grp >= npw || w >= N) return;
    int o = off[w], c = cnt[w];
    float4 a = b2f4(y2[(long long)w * nc4 + li]);
    int j = 0;
    for (; j + 4 <= c; j += 4) {
        int s0 = lst[o + j], s1 = lst[o + j + 1], s2 = lst[o + j + 2], s3 = lst[o + j + 3];
        float4 v0 = b2f4(y2[(long long)s0 * nc4 + li]);
        float4 v1 = b2f4(y2[(long long)s1 * nc4 + li]);
        float4 v2 = b2f4(y2[(long long)s2 * nc4 + li]);
        float4 v3 = b2f4(y2[(long long)s3 * nc4 + li]);
        a.x += (v0.x + v1.x) + (v2.x + v3.x);
        a.y += (v0.y + v1.y) + (v2.y + v3.y);
        a.z += (v0.z + v1.z) + (v2.z + v3.z);
        a.w += (v0.w + v1.w) + (v2.w + v3.w);
    }
    for (; j < c; j++) {
        float4 v = b2f4(y2[(long long)lst[o + j] * nc4 + li]);
        a.x += v.x; a.y += v.y; a.z += v.z; a.w += v.w;
    }
    float dd = dis[w];
    float4 b = *(const float4*)&bias2[4 * li];
    a.x = a.x * dd + b.x; a.y = a.y * dd + b.y;
    a.z = a.z * dd + b.z; a.w = a.w * dd + b.w;
    out4[(long long)w * nc4 + li] = a;
}

// --- load 8 source elements as bf16 (fp32->cvt or bf16 passthrough) ----------
__device__ __forceinline__ s16x8 load8bf(const void* A, int af, long long base) {
    s16x8 o;
    if (af) {
        float4 v0 = *(const float4*)((const float*)A + base);
        float4 v1 = *(const float4*)((const float*)A + base + 4);
        o[0] = (short)f2b(v0.x); o[1] = (short)f2b(v0.y);
        o[2] = (short)f2b(v0.z); o[3] = (short)f2b(v0.w);
        o[4] = (short)f2b(v1.x); o[5] = (short)f2b(v1.y);
        o[6] = (short)f2b(v1.z); o[7] = (short)f2b(v1.w);
    } else {
        o = *(const s16x8*)&((const unsigned short*)A)[base];
    }
    return o;
}

// --- MFMA GEMM: 128xMM tile per 256-thread block, full-K LDS staging ---------
// A: [NR][KK] fp32/bf16 (flag) or bf16 workspace; CAT: [x(128) | A2 bf16(64)]
// B: [KK][MM] fp32/bf16 (flag), staged transposed -> Bs[n][k]
// C: [NR][MM] bf16, optional per-row scale.
// Fragment layouts (gfx950, verified m89/m92): A lane=row(l&15),k=8*(l>>4)+j;
// B lane=col(l&15),k=8*(l>>4)+j; D col=l&15,row=(l>>4)*4+i.
template <int KK, int MM, bool CATMODE, bool ABF16, bool SCALE>
__global__ __launch_bounds__(256)
void gemm_mfma_k(const void* __restrict__ A, const int* __restrict__ fA,
                 const unsigned short* __restrict__ A2,
                 const void* __restrict__ B, const int* __restrict__ fB,
                 const float* __restrict__ dscale,
                 unsigned short* __restrict__ C, int NR) {
    constexpr int BM = 128;
    constexpr int Kp = KK + 8;              // +8 bf16 pad: 16B-aligned rows, 2-way banks
    constexpr int MT = (MM + 15) / 16;      // 16-col fragments
    constexpr int CPR = KK / 8;             // 8-elem chunks per row
    static_assert(KK % 32 == 0, "K must be multiple of 32");

    __shared__ __align__(16) unsigned short As[BM * Kp];
    __shared__ __align__(16) unsigned short Bs[MT * 16 * Kp];

    const int t = threadIdx.x;
    const long long m0 = (long long)blockIdx.x * BM;
    const int af = fA ? fA[0] : 1;
    const int bfv = fB ? fB[0] : 1;

    // ---- stage A (bf16, zero-padded rows past NR) ----
    for (int idx = t; idx < BM * CPR; idx += 256) {
        int r = idx / CPR;
        int kc = (idx - r * CPR) * 8;
        long long gr = m0 + r;
        s16x8 v = {0, 0, 0, 0, 0, 0, 0, 0};
        if (gr < NR) {
            if constexpr (CATMODE) {
                if (kc < 128) v = load8bf(A, af, gr * 128 + kc);
                else v = *(const s16x8*)&A2[gr * 64 + (kc - 128)];
            } else if constexpr (ABF16) {
                v = *(const s16x8*)&((const unsigned short*)A)[gr * KK + kc];
            } else {
                v = load8bf(A, af, gr * (long long)KK + kc);
            }
        }
        *(s16x8*)&As[r * Kp + kc] = v;
    }

    // ---- stage B transposed (Bs[n][k]), zero-pad cols [MM, MT*16) ----
    for (int e = t; e < KK * MM; e += 256) {
        int k = e / MM;
        int n = e - k * MM;
        Bs[n * Kp + k] = f2b(ldf(B, bfv, e));
    }
    if constexpr (MT * 16 != MM) {
        for (int e = t; e < (MT * 16 - MM) * KK; e += 256) {
            int n = MM + e / KK;
            int k = e - (e / KK) * KK;
            Bs[n * Kp + k] = 0;
        }
    }
    __syncthreads();

    // ---- MFMA: wave owns 32 rows (2 row-frags), all MT col-frags ----
    const int wid = t >> 6, lane = t & 63;
    const int r0 = wid * 32;
    const int arow = lane & 15;
    const int kgrp = lane >> 4;

    f32x4 acc0[MT] = {};
    f32x4 acc1[MT] = {};
#pragma unroll
    for (int kc = 0; kc < KK; kc += 32) {
        const int kb = kc + kgrp * 8;
        s16x8 a0 = *(const s16x8*)&As[(r0 + arow) * Kp + kb];
        s16x8 a1 = *(const s16x8*)&As[(r0 + 16 + arow) * Kp + kb];
#pragma unroll
        for (int m = 0; m < MT; m++) {
            s16x8 b = *(const s16x8*)&Bs[(m * 16 + arow) * Kp + kb];
            acc0[m] = __builtin_amdgcn_mfma_f32_16x16x32_bf16(a0, b, acc0[m], 0, 0, 0);
            acc1[m] = __builtin_amdgcn_mfma_f32_16x16x32_bf16(a1, b, acc1[m], 0, 0, 0);
        }
    }

    // ---- store: D col=lane&15, row=(lane>>4)*4+i ----
    const int col0 = lane & 15;
    const int rsub = (lane >> 4) * 4;
#pragma unroll
    for (int h = 0; h < 2; h++) {
#pragma unroll
        for (int i = 0; i < 4; i++) {
            long long r = m0 + r0 + h * 16 + rsub + i;
            if (r < NR) {
                float s = SCALE ? dscale[r] : 1.f;
#pragma unroll
                for (int m = 0; m < MT; m++) {
                    int col = m * 16 + col0;
                    float val = h ? acc1[m][i] : acc0[m][i];
                    if (MT * 16 == MM || col < MM)
                        C[r * MM + col] = f2b(val * s);
                }
            }
        }
    }
}

static inline dim3 g1d(long long n, int b) { return dim3((unsigned)((n + b - 1) / b)); }
static inline int imin(int a, int b) { return a < b ? a : b; }

extern "C" void kernel_launch(void* const* d_in, const int* in_sizes, int n_in,
                              void* d_out, int out_size, void* d_ws, size_t ws_size,
                              hipStream_t stream) {
    const int N  = in_sizes[0] / 128;   // 100000
    const int E  = in_sizes[1] / 2;     // 1600000
    const int P  = in_sizes[2] / 2;     // 800000
    const int HE = 20000;
    const int NC = in_sizes[9] / 64;    // 40
    const int nc4 = NC / 4;             // 10
    const int npw = 64 / nc4;           // 6

    const void* x    = d_in[0];
    const int*  ew   = (const int*)d_in[1];
    const int*  hw   = (const int*)d_in[2];
    const void* W_h1 = d_in[3];
    const void* b_h1 = d_in[4];
    const void* W_h2 = d_in[5];
    const void* b_h2 = d_in[6];
    const void* W_c1 = d_in[7];
    const void* b_c1 = d_in[8];
    const void* W_c2 = d_in[9];
    const void* b_c2 = d_in[10];
    const void* W_lp = d_in[11];
    const void* b_lp = d_in[12];

    int shN = 0; while (((N - 1) >> shN) >= 256) shN++;   // 9
    int shH = 0; while (((HE - 1) >> shH) >= 256) shH++;  // 7

    // ---- workspace ----
    char* wp = (char*)d_ws;
    auto allocF = [&](size_t n) { float* p = (float*)wp; wp += n * 4; return p; };
    auto allocI = [&](size_t n) { int* p = (int*)wp; wp += n * 4; return p; };
    unsigned short* ub  = (unsigned short*)allocF((size_t)N * 32);   // bf16 N*64 (GEMM out)
    unsigned short* hb  = (unsigned short*)allocF((size_t)N * 32);   // bf16 N*64 (gather out)
    unsigned short* efb = (unsigned short*)allocF((size_t)HE * 32);  // bf16 HE*64
    float* dis   = allocF(N);
    float* Dinv  = allocF(N);
    float* Binv  = allocF(HE);
    float* Wlp2  = allocF((size_t)64 * NC);
    float* bias2 = allocF(NC);
    int* ecnt  = allocI(N);
    int* pcntN = allocI(N);
    int* pcntH = allocI(HE);
    int* eoff  = allocI(N);
    int* poffN = allocI(N);
    int* poffH = allocI(HE);
    int* esrc  = allocI(E);
    int* pheL  = allocI(P);
    int* pniL  = allocI(P);
    int* gBkt  = allocI(768);
    int* bkOff = allocI(768);
    int* gcur  = allocI(768);
    int* FL    = allocI(16);
    unsigned* pbuf = (unsigned*)allocI((size_t)E + 2 * (size_t)P);

    dim3 b256(256), d1(1);

    // ---- dtype detection ----
    DPtrs dp;
    const void* farr[11] = {x, W_h1, b_h1, W_h2, b_h2, W_c1, b_c1, W_c2, b_c2, W_lp, b_lp};
    const int   fsz[11]  = {in_sizes[0], in_sizes[3], in_sizes[4], in_sizes[5], in_sizes[6],
                            in_sizes[7], in_sizes[8], in_sizes[9], in_sizes[10], in_sizes[11],
                            in_sizes[12]};
    for (int i = 0; i < 11; ++i) { dp.p[i] = farr[i]; dp.n[i] = fsz[i]; }
    dp.p[11] = ew; dp.n[11] = imin(E, 1024);
    dp.p[12] = hw; dp.n[12] = imin(P, 1024);
    detect_k<<<dim3(13), b256, 0, stream>>>(dp, FL);
    const int* fX   = FL + 0;
    const int* fWh1 = FL + 1,  *fbh1 = FL + 2;
    const int* fWh2 = FL + 3,  *fbh2 = FL + 4;
    const int* fWc1 = FL + 5,  *fbc1 = FL + 6;
    const int* fWc2 = FL + 7,  *fbc2 = FL + 8;
    const int* fWlp = FL + 9,  *fblp = FL + 10;

    // ---- CSR build ----
    hipMemsetAsync(gBkt, 0, 768 * 4, stream);
    bucket_count_k<<<dim3(512), b256, 0, stream>>>(ew, hw, FL, gBkt, E, P, N, HE, shN, shH);
    bucket_scan_k<<<d1, b256, 0, stream>>>(gBkt, bkOff, gcur, E, P);
    {
        long long T = (long long)E + P;
        int nChunks = (int)((T + PCHUNK - 1) / PCHUNK);
        bucket_place_k<<<dim3(nChunks), b256, 0, stream>>>(ew, hw, FL, gcur, pbuf,
                                                           E, P, N, HE, shN, shH);
    }
    build_k<<<dim3(768), b256, 0, stream>>>(pbuf, gBkt, bkOff,
                                            eoff, ecnt, esrc,
                                            poffN, pcntN, pheL,
                                            poffH, pcntH, pniL,
                                            E, P, N, HE, shN, shH);

    // ---- norms + fused tail weights ----
    norms_k<<<g1d(2 * N + HE, 256), b256, 0, stream>>>(ecnt, pcntN, pcntH, dis, Dinv, Binv, N, HE);
    wlp2_k<<<d1, b256, (64 * NC + NC * NC) * 4, stream>>>(
        W_c2, fWc2, W_lp, fWlp, b_c2, fbc2, b_lp, fblp, Wlp2, bias2, NC);

    const dim3 mfmaGrid((N + 127) / 128);
    const dim3 gatN16(g1d((long long)N * 16, 256));
    const dim3 gatH16(g1d((long long)HE * 16, 256));
    const dim3 gatNC(g1d((long long)((N + npw - 1) / npw) * 64, 256));

    // ---- hyperconv 1 ----
    gemm_mfma_k<128, 64, false, false, false><<<mfmaGrid, b256, 0, stream>>>(
        x, fX, nullptr, W_h1, fWh1, nullptr, ub, N);
    gat_n2e_k<<<gatH16, b256, 0, stream>>>((const ushort4*)ub, poffH, pcntH, pniL, Binv, (ushort4*)efb, HE);
    gat_e2n_k<true><<<gatN16, b256, 0, stream>>>((const ushort4*)efb, poffN, pcntN, pheL, Dinv, b_h1, fbh1, (ushort4*)hb, N);

    // ---- hyperconv 2 ----
    gemm_mfma_k<64, 64, false, true, false><<<mfmaGrid, b256, 0, stream>>>(
        hb, nullptr, nullptr, W_h2, fWh2, nullptr, ub, N);
    gat_n2e_k<<<gatH16, b256, 0, stream>>>((const ushort4*)ub, poffH, pcntH, pniL, Binv, (ushort4*)efb, HE);
    gat_e2n_k<false><<<gatN16, b256, 0, stream>>>((const ushort4*)efb, poffN, pcntN, pheL, Dinv, b_h2, fbh2, (ushort4*)hb, N);
    // hb = x_hyper (bf16)

    // ---- gcn 1: y = ([x|x_hyper] @ W_c1) * dis (bf16), then gather ----
    gemm_mfma_k<192, 64, true, false, true><<<mfmaGrid, b256, 0, stream>>>(
        x, fX, hb, W_c1, fWc1, dis, ub, N);
    gcn_gat_k<true><<<gatN16, b256, 0, stream>>>((const ushort4*)ub, eoff, ecnt, esrc, dis, b_c1, fbc1, (ushort4*)hb, N);

    // ---- gcn 2 + final linear fused: y2 = (hb @ Wlp2) * dis (bf16), gather ----
    gemm_mfma_k<64, 40, false, true, true><<<mfmaGrid, b256, 0, stream>>>(
        hb, nullptr, nullptr, Wlp2, nullptr, dis, ub, N);
    gcn_gatM_k<<<gatNC, b256, 0, stream>>>((const ushort4*)ub, eoff, ecnt, esrc, dis, bias2, (float4*)d_out, N, nc4, npw);
}

// Round 2
// 472.926 us; speedup vs baseline: 1.0263x; 1.0263x over previous
//
#include <hip/hip_runtime.h>
#include <hip/hip_bf16.h>

// ---------------------------------------------------------------------------
// LPGCNHyperConvAblation, round 11: LDS-free MFMA GEMMs. A fragments loaded
// directly from global (no reuse -> no staging); B pre-transposed to bf16
// once (bprep_k) and read through L1/L2. bucket_place PCHUNK 8192->2048 for
// occupancy. Everything else unchanged from round 10.
// ---------------------------------------------------------------------------

typedef __attribute__((ext_vector_type(8))) short s16x8;
typedef __attribute__((ext_vector_type(4))) float f32x4;

__device__ __forceinline__ float ldf(const void* p, int f32, long long i) {
    if (f32) return ((const float*)p)[i];
    unsigned v = ((unsigned)((const unsigned short*)p)[i]) << 16;
    return __uint_as_float(v);
}

__device__ __forceinline__ int ldi(const int* __restrict__ w, int i64, long long i, int lim) {
    int v = i64 ? w[2 * i] : w[i];
    return ((unsigned)v < (unsigned)lim) ? v : 0;
}

__device__ __forceinline__ float b2f(unsigned short u) {
    return __uint_as_float(((unsigned)u) << 16);
}
__device__ __forceinline__ unsigned short f2b(float f) {
    __hip_bfloat16 h = __float2bfloat16(f);
    return *reinterpret_cast<unsigned short*>(&h);
}
__device__ __forceinline__ float4 b2f4(ushort4 u) {
    return make_float4(b2f(u.x), b2f(u.y), b2f(u.z), b2f(u.w));
}
__device__ __forceinline__ ushort4 f2b4(float4 v) {
    ushort4 u; u.x = f2b(v.x); u.y = f2b(v.y); u.z = f2b(v.z); u.w = f2b(v.w);
    return u;
}

// --- fused dtype detection ---------------------------------------------------
struct DPtrs { const void* p[13]; int n[13]; };

__global__ void detect_k(DPtrs dp, int* __restrict__ flags) {
    int b = blockIdx.x;
    __shared__ int cnt;
    if (threadIdx.x == 0) cnt = 0;
    __syncthreads();
    int c = 0;
    if (b < 11) {
        const unsigned short* u = (const unsigned short*)dp.p[b];
        int np = dp.n[b]; if (np > 2048) np = 2048;
        for (int i = threadIdx.x; i < np; i += blockDim.x) {
            unsigned e = (u[i] >> 7) & 0xFFu;
            if (e != 0u && (e < 90u || e > 160u)) c++;
        }
        atomicAdd(&cnt, c);
        __syncthreads();
        if (threadIdx.x == 0) flags[b] = (cnt * 8 > np) ? 1 : 0;
    } else {
        const int* w = (const int*)dp.p[b];
        int np = dp.n[b]; if (np > 1024) np = 1024;
        for (int i = threadIdx.x; i < np; i += blockDim.x)
            if (w[2 * i + 1] != 0) c++;
        atomicAdd(&cnt, c);
        __syncthreads();
        if (threadIdx.x == 0) flags[b] = (cnt == 0) ? 1 : 0;
    }
}

// --- CSR build (atomic-free pipeline) ----------------------------------------
struct Item { int b1; unsigned p1; int b2; unsigned p2; };

__device__ __forceinline__ Item decode(const int* __restrict__ ew, const int* __restrict__ hw,
                                       const int* __restrict__ FL, long long i,
                                       int E, int P, int N, int HE, int shN, int shH) {
    Item it; it.b2 = -1; it.p2 = 0;
    if (i < E) {
        int g = FL[11];
        int key = ldi(ew, g, (long long)E + i, N);
        int val = ldi(ew, g, i, N);
        it.b1 = key >> shN;
        it.p1 = ((unsigned)(key & ((1 << shN) - 1)) << 20) | (unsigned)val;
    } else {
        long long j = i - E;
        int g = FL[12];
        int nd = ldi(hw, g, j, N);
        int he = ldi(hw, g, (long long)P + j, HE);
        it.b1 = 256 + (nd >> shN);
        it.p1 = ((unsigned)(nd & ((1 << shN) - 1)) << 20) | (unsigned)he;
        it.b2 = 512 + (he >> shH);
        it.p2 = ((unsigned)(he & ((1 << shH) - 1)) << 20) | (unsigned)nd;
    }
    return it;
}

__global__ void bucket_count_k(const int* __restrict__ ew, const int* __restrict__ hw,
                               const int* __restrict__ FL, int* __restrict__ gcnt,
                               int E, int P, int N, int HE, int shN, int shH) {
    __shared__ int hist[768];
    int t = threadIdx.x;
    for (int b = t; b < 768; b += 256) hist[b] = 0;
    __syncthreads();
    long long T = (long long)E + P;
    long long stride = (long long)gridDim.x * 256;
    for (long long i = (long long)blockIdx.x * 256 + t; i < T; i += stride) {
        Item it = decode(ew, hw, FL, i, E, P, N, HE, shN, shH);
        atomicAdd(&hist[it.b1], 1);
        if (it.b2 >= 0) atomicAdd(&hist[it.b2], 1);
    }
    __syncthreads();
    for (int b = t; b < 768; b += 256) {
        int h = hist[b];
        if (h) atomicAdd(&gcnt[b], h);
    }
}

__global__ void bucket_scan_k(const int* __restrict__ gcnt, int* __restrict__ bkOff,
                              int* __restrict__ gcur, int E, int P) {
    __shared__ int sh[256];
    int t = threadIdx.x;
    long long rbase[3] = {0, (long long)E, (long long)E + P};
    for (int c = 0; c < 3; c++) {
        int v = gcnt[c * 256 + t];
        sh[t] = v;
        __syncthreads();
        for (int o = 1; o < 256; o <<= 1) {
            int y = (t >= o) ? sh[t - o] : 0;
            __syncthreads();
            sh[t] += y;
            __syncthreads();
        }
        int excl = sh[t] - v;
        bkOff[c * 256 + t] = excl;
        gcur[c * 256 + t] = (int)(rbase[c] + excl);
        __syncthreads();
    }
}

#define PCHUNK 2048

__global__ void bucket_place_k(const int* __restrict__ ew, const int* __restrict__ hw,
                               const int* __restrict__ FL, int* __restrict__ gcur,
                               unsigned* __restrict__ pbuf,
                               int E, int P, int N, int HE, int shN, int shH) {
    __shared__ int hist[768];
    __shared__ int cur[768];
    long long T = (long long)E + P;
    long long start = (long long)blockIdx.x * PCHUNK;
    long long end = start + PCHUNK; if (end > T) end = T;
    int t = threadIdx.x;
    for (int b = t; b < 768; b += 256) hist[b] = 0;
    __syncthreads();
    for (long long i = start + t; i < end; i += 256) {
        Item it = decode(ew, hw, FL, i, E, P, N, HE, shN, shH);
        atomicAdd(&hist[it.b1], 1);
        if (it.b2 >= 0) atomicAdd(&hist[it.b2], 1);
    }
    __syncthreads();
    for (int b = t; b < 768; b += 256) {
        int h = hist[b];
        cur[b] = h ? atomicAdd(&gcur[b], h) : 0;
    }
    __syncthreads();
    for (long long i = start + t; i < end; i += 256) {
        Item it = decode(ew, hw, FL, i, E, P, N, HE, shN, shH);
        int s1 = atomicAdd(&cur[it.b1], 1);
        pbuf[s1] = it.p1;
        if (it.b2 >= 0) {
            int s2 = atomicAdd(&cur[it.b2], 1);
            pbuf[s2] = it.p2;
        }
    }
}

__global__ void build_k(const unsigned* __restrict__ pbuf,
                        const int* __restrict__ gcnt, const int* __restrict__ bkOff,
                        int* __restrict__ eoff, int* __restrict__ ecnt, int* __restrict__ esrc,
                        int* __restrict__ poffN, int* __restrict__ pcntN, int* __restrict__ pheL,
                        int* __restrict__ poffH, int* __restrict__ pcntH, int* __restrict__ pniL,
                        int E, int P, int N, int HE, int shN, int shH) {
    __shared__ int hist[512];
    __shared__ int offs[512];
    __shared__ int s2[256];
    int b = blockIdx.x, t = threadIdx.x;
    int csr = b >> 8, lb = b & 255;
    int sh    = (csr == 2) ? shH : shN;
    int nkeys = (csr == 2) ? HE : N;
    int span = 1 << sh;
    int keyBase = lb << sh;
    if (keyBase >= nkeys) return;
    int keyEnd = keyBase + span; if (keyEnd > nkeys) keyEnd = nkeys;
    int cnt = gcnt[b];
    long long rbase = (csr == 0) ? 0 : ((csr == 1) ? (long long)E : (long long)E + P);
    long long pstart = rbase + bkOff[b];
    int lstBase = bkOff[b];
    int* off  = (csr == 0) ? eoff : ((csr == 1) ? poffN : poffH);
    int* cntA = (csr == 0) ? ecnt : ((csr == 1) ? pcntN : pcntH);
    int* lst  = (csr == 0) ? esrc : ((csr == 1) ? pheL : pniL);

    for (int k = t; k < 512; k += 256) hist[k] = 0;
    __syncthreads();
    for (int i = t; i < cnt; i += 256)
        atomicAdd(&hist[pbuf[pstart + i] >> 20], 1);
    __syncthreads();
    int a0 = hist[2 * t], a1 = hist[2 * t + 1];
    s2[t] = a0 + a1;
    __syncthreads();
    for (int o = 1; o < 256; o <<= 1) {
        int y = (t >= o) ? s2[t - o] : 0;
        __syncthreads();
        s2[t] += y;
        __syncthreads();
    }
    int excl = s2[t] - (a0 + a1);
    offs[2 * t] = excl;
    offs[2 * t + 1] = excl + a0;
    __syncthreads();
    for (int k = keyBase + t; k < keyEnd; k += 256) {
        off[k]  = lstBase + offs[k - keyBase];
        cntA[k] = hist[k - keyBase];
    }
    __syncthreads();
    for (int i = t; i < cnt; i += 256) {
        unsigned u = pbuf[pstart + i];
        int lk = u >> 20;
        int slot = atomicAdd(&offs[lk], 1);
        lst[lstBase + slot] = (int)(u & 0xFFFFFu);
    }
}

// --- fused norm factors ------------------------------------------------------
__global__ void norms_k(const int* __restrict__ ecnt, const int* __restrict__ pcntN,
                        const int* __restrict__ pcntH, float* __restrict__ dis,
                        float* __restrict__ Dinv, float* __restrict__ Binv, int N, int HE) {
    int i = blockIdx.x * blockDim.x + threadIdx.x;
    if (i < N) dis[i] = rsqrtf((float)(ecnt[i] + 1));
    else if (i < 2 * N) { int c = pcntN[i - N]; Dinv[i - N] = c ? (1.f / (float)c) : 0.f; }
    else if (i < 2 * N + HE) { int c = pcntH[i - 2 * N]; Binv[i - 2 * N] = c ? (1.f / (float)c) : 0.f; }
}

// --- Wlp2 = W_c2 @ W_lp, bias2 = b_c2 @ W_lp + b_lp  (LDS-staged) ------------
__global__ void wlp2_k(const void* Wc2, const int* fWc2, const void* Wlp, const int* fWlp,
                       const void* bc2, const int* fbc2, const void* blp, const int* fblp,
                       float* __restrict__ Wlp2, float* __restrict__ bias2, int NC) {
    extern __shared__ float sm[];
    float* sW2 = sm;                 // 64*NC  (W_c2)
    float* sLP = sm + 64 * NC;       // NC*NC  (W_lp)
    int t = threadIdx.x;
    int fw2 = fWc2[0], flp = fWlp[0];
    for (int e = t; e < 64 * NC; e += blockDim.x) sW2[e] = ldf(Wc2, fw2, e);
    for (int e = t; e < NC * NC; e += blockDim.x) sLP[e] = ldf(Wlp, flp, e);
    __syncthreads();
    for (int e = t; e < 64 * NC; e += blockDim.x) {
        int r = e / NC, c = e % NC;
        float s = 0.f;
        for (int k = 0; k < NC; k++) s = fmaf(sW2[r * NC + k], sLP[k * NC + c], s);
        Wlp2[e] = s;
    }
    if (t < NC) {
        float s = ldf(blp, fblp[0], t);
        int fb2 = fbc2[0];
        for (int k = 0; k < NC; k++) s = fmaf(ldf(bc2, fb2, k), sLP[k * NC + t], s);
        bias2[t] = s;
    }
}

// --- B prep: Bt[m][k] = bf16(B[k][m]), zero-pad m in [M, Mp) -----------------
struct BP { const void* B; const int* fB; int K; int M; int Mp; unsigned short* out; };

__global__ void bprep_k(BP p0, BP p1, BP p2, BP p3) {
    BP p = (blockIdx.x == 0) ? p0 : (blockIdx.x == 1) ? p1 : (blockIdx.x == 2) ? p2 : p3;
    int fb = p.fB ? p.fB[0] : 1;
    int tot = p.Mp * p.K;
    for (int e = threadIdx.x; e < tot; e += blockDim.x) {
        int m = e / p.K, k = e - m * p.K;
        float v = (m < p.M) ? ldf(p.B, fb, (long long)k * p.M + m) : 0.f;
        p.out[e] = f2b(v);
    }
}

// --- bf16 gathers: 4 rows/wave, 16 lanes x ushort4 (D=64) --------------------
__global__ void gat_n2e_k(const ushort4* __restrict__ xw, const int* __restrict__ off,
                          const int* __restrict__ cnt, const int* __restrict__ lst,
                          const float* __restrict__ Binv, ushort4* __restrict__ ef, int HE) {
    int idx = blockIdx.x * blockDim.x + threadIdx.x;
    int e = idx >> 4, l = idx & 15;
    if (e >= HE) return;
    int o = off[e], c = cnt[e];
    float4 a = make_float4(0.f, 0.f, 0.f, 0.f);
    int j = 0;
    for (; j + 4 <= c; j += 4) {
        int s0 = lst[o + j], s1 = lst[o + j + 1], s2 = lst[o + j + 2], s3 = lst[o + j + 3];
        float4 v0 = b2f4(xw[((long long)s0 << 4) + l]);
        float4 v1 = b2f4(xw[((long long)s1 << 4) + l]);
        float4 v2 = b2f4(xw[((long long)s2 << 4) + l]);
        float4 v3 = b2f4(xw[((long long)s3 << 4) + l]);
        a.x += (v0.x + v1.x) + (v2.x + v3.x);
        a.y += (v0.y + v1.y) + (v2.y + v3.y);
        a.z += (v0.z + v1.z) + (v2.z + v3.z);
        a.w += (v0.w + v1.w) + (v2.w + v3.w);
    }
    for (; j < c; j++) {
        float4 v = b2f4(xw[((long long)lst[o + j] << 4) + l]);
        a.x += v.x; a.y += v.y; a.z += v.z; a.w += v.w;
    }
    float bi = Binv[e];
    a.x *= bi; a.y *= bi; a.z *= bi; a.w *= bi;
    ef[((long long)e << 4) + l] = f2b4(a);
}

// hyperedge -> node: out = Dinv*sum + bias (+relu), bf16 out
template <bool RELU>
__global__ void gat_e2n_k(const ushort4* __restrict__ ef, const int* __restrict__ off,
                          const int* __restrict__ cnt, const int* __restrict__ lst,
                          const float* __restrict__ Dinv, const void* __restrict__ bias,
                          const int* __restrict__ fb, ushort4* __restrict__ out, int N) {
    int idx = blockIdx.x * blockDim.x + threadIdx.x;
    int w = idx >> 4, l = idx & 15;
    if (w >= N) return;
    int o = off[w], c = cnt[w];
    float4 a = make_float4(0.f, 0.f, 0.f, 0.f);
    int j = 0;
    for (; j + 4 <= c; j += 4) {
        int s0 = lst[o + j], s1 = lst[o + j + 1], s2 = lst[o + j + 2], s3 = lst[o + j + 3];
        float4 v0 = b2f4(ef[((long long)s0 << 4) + l]);
        float4 v1 = b2f4(ef[((long long)s1 << 4) + l]);
        float4 v2 = b2f4(ef[((long long)s2 << 4) + l]);
        float4 v3 = b2f4(ef[((long long)s3 << 4) + l]);
        a.x += (v0.x + v1.x) + (v2.x + v3.x);
        a.y += (v0.y + v1.y) + (v2.y + v3.y);
        a.z += (v0.z + v1.z) + (v2.z + v3.z);
        a.w += (v0.w + v1.w) + (v2.w + v3.w);
    }
    for (; j < c; j++) {
        float4 v = b2f4(ef[((long long)lst[o + j] << 4) + l]);
        a.x += v.x; a.y += v.y; a.z += v.z; a.w += v.w;
    }
    float di = Dinv[w];
    int fbv = fb[0];
    float4 b = make_float4(ldf(bias, fbv, 4 * l), ldf(bias, fbv, 4 * l + 1),
                           ldf(bias, fbv, 4 * l + 2), ldf(bias, fbv, 4 * l + 3));
    a.x = a.x * di + b.x; a.y = a.y * di + b.y;
    a.z = a.z * di + b.z; a.w = a.w * di + b.w;
    if (RELU) {
        a.x = fmaxf(a.x, 0.f); a.y = fmaxf(a.y, 0.f);
        a.z = fmaxf(a.z, 0.f); a.w = fmaxf(a.w, 0.f);
    }
    out[((long long)w << 4) + l] = f2b4(a);
}

// GCN aggregation on pre-scaled bf16 y, bf16 out
template <bool RELU>
__global__ void gcn_gat_k(const ushort4* __restrict__ y, const int* __restrict__ off,
                          const int* __restrict__ cnt, const int* __restrict__ lst,
                          const float* __restrict__ dis, const void* __restrict__ bias,
                          const int* __restrict__ fb, ushort4* __restrict__ out, int N) {
    int idx = blockIdx.x * blockDim.x + threadIdx.x;
    int w = idx >> 4, l = idx & 15;
    if (w >= N) return;
    int o = off[w], c = cnt[w];
    float4 a = b2f4(y[((long long)w << 4) + l]);
    int j = 0;
    for (; j + 4 <= c; j += 4) {
        int s0 = lst[o + j], s1 = lst[o + j + 1], s2 = lst[o + j + 2], s3 = lst[o + j + 3];
        float4 v0 = b2f4(y[((long long)s0 << 4) + l]);
        float4 v1 = b2f4(y[((long long)s1 << 4) + l]);
        float4 v2 = b2f4(y[((long long)s2 << 4) + l]);
        float4 v3 = b2f4(y[((long long)s3 << 4) + l]);
        a.x += (v0.x + v1.x) + (v2.x + v3.x);
        a.y += (v0.y + v1.y) + (v2.y + v3.y);
        a.z += (v0.z + v1.z) + (v2.z + v3.z);
        a.w += (v0.w + v1.w) + (v2.w + v3.w);
    }
    for (; j < c; j++) {
        float4 v = b2f4(y[((long long)lst[o + j] << 4) + l]);
        a.x += v.x; a.y += v.y; a.z += v.z; a.w += v.w;
    }
    float dd = dis[w];
    int fbv = fb[0];
    float4 b = make_float4(ldf(bias, fbv, 4 * l), ldf(bias, fbv, 4 * l + 1),
                           ldf(bias, fbv, 4 * l + 2), ldf(bias, fbv, 4 * l + 3));
    a.x = a.x * dd + b.x; a.y = a.y * dd + b.y;
    a.z = a.z * dd + b.z; a.w = a.w * dd + b.w;
    if (RELU) {
        a.x = fmaxf(a.x, 0.f); a.y = fmaxf(a.y, 0.f);
        a.z = fmaxf(a.z, 0.f); a.w = fmaxf(a.w, 0.f);
    }
    out[((long long)w << 4) + l] = f2b4(a);
}

// final GCN aggregation over bf16 y2 (M=NC), writes d_out fp32
__global__ void gcn_gatM_k(const ushort4* __restrict__ y2, const int* __restrict__ off,
                           const int* __restrict__ cnt, const int* __restrict__ lst,
                           const float* __restrict__ dis, const float* __restrict__ bias2,
                           float4* __restrict__ out4, int N, int nc4, int npw) {
    int idx = blockIdx.x * blockDim.x + threadIdx.x;
    int wave = idx >> 6, l64 = idx & 63;
    int grp = l64 / 10, li = l64 - grp * 10;
    if (nc4 != 10) { grp = l64 / nc4; li = l64 - grp * nc4; }
    int w = wave * npw + grp;
    if (grp >= npw || w >= N) return;
    int o = off[w], c = cnt[w];
    float4 a = b2f4(y2[(long long)w * nc4 + li]);
    int j = 0;
    for (; j + 4 <= c; j += 4) {
        int s0 = lst[o + j], s1 = lst[o + j + 1], s2 = lst[o + j + 2], s3 = lst[o + j + 3];
        float4 v0 = b2f4(y2[(long long)s0 * nc4 + li]);
        float4 v1 = b2f4(y2[(long long)s1 * nc4 + li]);
        float4 v2 = b2f4(y2[(long long)s2 * nc4 + li]);
        float4 v3 = b2f4(y2[(long long)s3 * nc4 + li]);
        a.x += (v0.x + v1.x) + (v2.x + v3.x);
        a.y += (v0.y + v1.y) + (v2.y + v3.y);
        a.z += (v0.z + v1.z) + (v2.z + v3.z);
        a.w += (v0.w + v1.w) + (v2.w + v3.w);
    }
    for (; j < c; j++) {
        float4 v = b2f4(y2[(long long)lst[o + j] * nc4 + li]);
        a.x += v.x; a.y += v.y; a.z += v.z; a.w += v.w;
    }
    float dd = dis[w];
    float4 b = *(const float4*)&bias2[4 * li];
    a.x = a.x * dd + b.x; a.y = a.y * dd + b.y;
    a.z = a.z * dd + b.z; a.w = a.w * dd + b.w;
    out4[(long long)w * nc4 + li] = a;
}

// --- load 8 source elements as bf16 (fp32->cvt or bf16 passthrough) ----------
__device__ __forceinline__ s16x8 load8bf(const void* A, int af, long long base) {
    s16x8 o;
    if (af) {
        float4 v0 = *(const float4*)((const float*)A + base);
        float4 v1 = *(const float4*)((const float*)A + base + 4);
        o[0] = (short)f2b(v0.x); o[1] = (short)f2b(v0.y);
        o[2] = (short)f2b(v0.z); o[3] = (short)f2b(v0.w);
        o[4] = (short)f2b(v1.x); o[5] = (short)f2b(v1.y);
        o[6] = (short)f2b(v1.z); o[7] = (short)f2b(v1.w);
    } else {
        o = *(const s16x8*)&((const unsigned short*)A)[base];
    }
    return o;
}

// --- LDS-free MFMA GEMM: one wave = 32 rows x MM cols, B^T bf16 from global --
// A: [NR][KK] fp32/bf16 (flag) or bf16 workspace; CAT: [x(128) | A2 bf16(64)]
// Bt: [Mp][KK] bf16 (pre-transposed, zero-padded cols), L1/L2-resident.
// Fragment layouts (gfx950, verified m89/m92): A lane=row(l&15),k=8*(l>>4)+j;
// B lane=col(l&15),k=8*(l>>4)+j; D col=l&15,row=(l>>4)*4+i.
template <int KK, int MM, bool CATMODE, bool ABF16, bool SCALE>
__global__ __launch_bounds__(256)
void gemm_mfma2_k(const void* __restrict__ A, const int* __restrict__ fA,
                  const unsigned short* __restrict__ A2,
                  const unsigned short* __restrict__ Bt,
                  const float* __restrict__ dscale,
                  unsigned short* __restrict__ C, int NR) {
    constexpr int MT = (MM + 15) / 16;
    static_assert(KK % 32 == 0, "K must be multiple of 32");

    const int t = threadIdx.x;
    const int wid = t >> 6, lane = t & 63;
    const long long r0 = ((long long)blockIdx.x * 4 + wid) * 32;
    if (r0 >= NR) return;

    const int af = fA ? fA[0] : 1;
    const int arow = lane & 15;
    const int kgrp = lane >> 4;
    long long ra = r0 + arow;      if (ra > NR - 1) ra = NR - 1;
    long long rb = r0 + 16 + arow; if (rb > NR - 1) rb = NR - 1;

    f32x4 acc0[MT] = {};
    f32x4 acc1[MT] = {};
#pragma unroll
    for (int kc = 0; kc < KK; kc += 32) {
        const int kb = kc + kgrp * 8;
        s16x8 a0, a1;
        if constexpr (CATMODE) {
            if (kc < 128) {   // kb in [kc, kc+24] < 128 since kc <= 96
                a0 = load8bf(A, af, ra * 128 + kb);
                a1 = load8bf(A, af, rb * 128 + kb);
            } else {
                a0 = *(const s16x8*)&A2[ra * 64 + (kb - 128)];
                a1 = *(const s16x8*)&A2[rb * 64 + (kb - 128)];
            }
        } else if constexpr (ABF16) {
            a0 = *(const s16x8*)&((const unsigned short*)A)[ra * KK + kb];
            a1 = *(const s16x8*)&((const unsigned short*)A)[rb * KK + kb];
        } else {
            a0 = load8bf(A, af, ra * (long long)KK + kb);
            a1 = load8bf(A, af, rb * (long long)KK + kb);
        }
#pragma unroll
        for (int m = 0; m < MT; m++) {
            s16x8 b = *(const s16x8*)&Bt[(m * 16 + arow) * KK + kb];
            acc0[m] = __builtin_amdgcn_mfma_f32_16x16x32_bf16(a0, b, acc0[m], 0, 0, 0);
            acc1[m] = __builtin_amdgcn_mfma_f32_16x16x32_bf16(a1, b, acc1[m], 0, 0, 0);
        }
    }

    // ---- store: D col=lane&15, row=(lane>>4)*4+i ----
    const int col0 = lane & 15;
    const int rsub = (lane >> 4) * 4;
#pragma unroll
    for (int h = 0; h < 2; h++) {
#pragma unroll
        for (int i = 0; i < 4; i++) {
            long long r = r0 + h * 16 + rsub + i;
            if (r < NR) {
                float s = SCALE ? dscale[r] : 1.f;
#pragma unroll
                for (int m = 0; m < MT; m++) {
                    int col = m * 16 + col0;
                    float val = h ? acc1[m][i] : acc0[m][i];
                    if (MT * 16 == MM || col < MM)
                        C[r * MM + col] = f2b(val * s);
                }
            }
        }
    }
}

static inline dim3 g1d(long long n, int b) { return dim3((unsigned)((n + b - 1) / b)); }
static inline int imin(int a, int b) { return a < b ? a : b; }

extern "C" void kernel_launch(void* const* d_in, const int* in_sizes, int n_in,
                              void* d_out, int out_size, void* d_ws, size_t ws_size,
                              hipStream_t stream) {
    const int N  = in_sizes[0] / 128;   // 100000
    const int E  = in_sizes[1] / 2;     // 1600000
    const int P  = in_sizes[2] / 2;     // 800000
    const int HE = 20000;
    const int NC = in_sizes[9] / 64;    // 40
    const int nc4 = NC / 4;             // 10
    const int npw = 64 / nc4;           // 6

    const void* x    = d_in[0];
    const int*  ew   = (const int*)d_in[1];
    const int*  hw   = (const int*)d_in[2];
    const void* W_h1 = d_in[3];
    const void* b_h1 = d_in[4];
    const void* W_h2 = d_in[5];
    const void* b_h2 = d_in[6];
    const void* W_c1 = d_in[7];
    const void* b_c1 = d_in[8];
    const void* W_c2 = d_in[9];
    const void* b_c2 = d_in[10];
    const void* W_lp = d_in[11];
    const void* b_lp = d_in[12];

    int shN = 0; while (((N - 1) >> shN) >= 256) shN++;   // 9
    int shH = 0; while (((HE - 1) >> shH) >= 256) shH++;  // 7

    // ---- workspace ----
    char* wp = (char*)d_ws;
    auto allocF = [&](size_t n) { float* p = (float*)wp; wp += n * 4; return p; };
    auto allocI = [&](size_t n) { int* p = (int*)wp; wp += n * 4; return p; };
    unsigned short* ub  = (unsigned short*)allocF((size_t)N * 32);   // bf16 N*64 (GEMM out)
    unsigned short* hb  = (unsigned short*)allocF((size_t)N * 32);   // bf16 N*64 (gather out)
    unsigned short* efb = (unsigned short*)allocF((size_t)HE * 32);  // bf16 HE*64
    float* dis   = allocF(N);
    float* Dinv  = allocF(N);
    float* Binv  = allocF(HE);
    float* Wlp2  = allocF((size_t)64 * NC);
    float* bias2 = allocF(NC);
    unsigned short* bt1 = (unsigned short*)allocF((size_t)64 * 128 / 2);  // W_h1^T bf16
    unsigned short* bt2 = (unsigned short*)allocF((size_t)64 * 64 / 2);   // W_h2^T bf16
    unsigned short* btc = (unsigned short*)allocF((size_t)64 * 192 / 2);  // W_c1^T bf16
    unsigned short* btl = (unsigned short*)allocF((size_t)48 * 64 / 2);   // Wlp2^T bf16
    int* ecnt  = allocI(N);
    int* pcntN = allocI(N);
    int* pcntH = allocI(HE);
    int* eoff  = allocI(N);
    int* poffN = allocI(N);
    int* poffH = allocI(HE);
    int* esrc  = allocI(E);
    int* pheL  = allocI(P);
    int* pniL  = allocI(P);
    int* gBkt  = allocI(768);
    int* bkOff = allocI(768);
    int* gcur  = allocI(768);
    int* FL    = allocI(16);
    unsigned* pbuf = (unsigned*)allocI((size_t)E + 2 * (size_t)P);

    dim3 b256(256), d1(1);

    // ---- dtype detection ----
    DPtrs dp;
    const void* farr[11] = {x, W_h1, b_h1, W_h2, b_h2, W_c1, b_c1, W_c2, b_c2, W_lp, b_lp};
    const int   fsz[11]  = {in_sizes[0], in_sizes[3], in_sizes[4], in_sizes[5], in_sizes[6],
                            in_sizes[7], in_sizes[8], in_sizes[9], in_sizes[10], in_sizes[11],
                            in_sizes[12]};
    for (int i = 0; i < 11; ++i) { dp.p[i] = farr[i]; dp.n[i] = fsz[i]; }
    dp.p[11] = ew; dp.n[11] = imin(E, 1024);
    dp.p[12] = hw; dp.n[12] = imin(P, 1024);
    detect_k<<<dim3(13), b256, 0, stream>>>(dp, FL);
    const int* fX   = FL + 0;
    const int* fWh1 = FL + 1,  *fbh1 = FL + 2;
    const int* fWh2 = FL + 3,  *fbh2 = FL + 4;
    const int* fWc1 = FL + 5,  *fbc1 = FL + 6;
    const int* fWc2 = FL + 7,  *fbc2 = FL + 8;
    const int* fWlp = FL + 9,  *fblp = FL + 10;

    // ---- CSR build ----
    hipMemsetAsync(gBkt, 0, 768 * 4, stream);
    bucket_count_k<<<dim3(512), b256, 0, stream>>>(ew, hw, FL, gBkt, E, P, N, HE, shN, shH);
    bucket_scan_k<<<d1, b256, 0, stream>>>(gBkt, bkOff, gcur, E, P);
    {
        long long T = (long long)E + P;
        int nChunks = (int)((T + PCHUNK - 1) / PCHUNK);
        bucket_place_k<<<dim3(nChunks), b256, 0, stream>>>(ew, hw, FL, gcur, pbuf,
                                                           E, P, N, HE, shN, shH);
    }
    build_k<<<dim3(768), b256, 0, stream>>>(pbuf, gBkt, bkOff,
                                            eoff, ecnt, esrc,
                                            poffN, pcntN, pheL,
                                            poffH, pcntH, pniL,
                                            E, P, N, HE, shN, shH);

    // ---- norms + fused tail weights + B transposes ----
    norms_k<<<g1d(2 * N + HE, 256), b256, 0, stream>>>(ecnt, pcntN, pcntH, dis, Dinv, Binv, N, HE);
    wlp2_k<<<d1, b256, (64 * NC + NC * NC) * 4, stream>>>(
        W_c2, fWc2, W_lp, fWlp, b_c2, fbc2, b_lp, fblp, Wlp2, bias2, NC);
    {
        BP p0 = {W_h1, fWh1, 128, 64, 64, bt1};
        BP p1 = {W_h2, fWh2,  64, 64, 64, bt2};
        BP p2 = {W_c1, fWc1, 192, 64, 64, btc};
        BP p3 = {Wlp2, nullptr, 64, NC, 48, btl};
        bprep_k<<<dim3(4), b256, 0, stream>>>(p0, p1, p2, p3);
    }

    const dim3 mfmaGrid((N + 127) / 128);
    const dim3 gatN16(g1d((long long)N * 16, 256));
    const dim3 gatH16(g1d((long long)HE * 16, 256));
    const dim3 gatNC(g1d((long long)((N + npw - 1) / npw) * 64, 256));

    // ---- hyperconv 1 ----
    gemm_mfma2_k<128, 64, false, false, false><<<mfmaGrid, b256, 0, stream>>>(
        x, fX, nullptr, bt1, nullptr, ub, N);
    gat_n2e_k<<<gatH16, b256, 0, stream>>>((const ushort4*)ub, poffH, pcntH, pniL, Binv, (ushort4*)efb, HE);
    gat_e2n_k<true><<<gatN16, b256, 0, stream>>>((const ushort4*)efb, poffN, pcntN, pheL, Dinv, b_h1, fbh1, (ushort4*)hb, N);

    // ---- hyperconv 2 ----
    gemm_mfma2_k<64, 64, false, true, false><<<mfmaGrid, b256, 0, stream>>>(
        hb, nullptr, nullptr, bt2, nullptr, ub, N);
    gat_n2e_k<<<gatH16, b256, 0, stream>>>((const ushort4*)ub, poffH, pcntH, pniL, Binv, (ushort4*)efb, HE);
    gat_e2n_k<false><<<gatN16, b256, 0, stream>>>((const ushort4*)efb, poffN, pcntN, pheL, Dinv, b_h2, fbh2, (ushort4*)hb, N);
    // hb = x_hyper (bf16)

    // ---- gcn 1: y = ([x|x_hyper] @ W_c1) * dis (bf16), then gather ----
    gemm_mfma2_k<192, 64, true, false, true><<<mfmaGrid, b256, 0, stream>>>(
        x, fX, hb, btc, dis, ub, N);
    gcn_gat_k<true><<<gatN16, b256, 0, stream>>>((const ushort4*)ub, eoff, ecnt, esrc, dis, b_c1, fbc1, (ushort4*)hb, N);

    // ---- gcn 2 + final linear fused: y2 = (hb @ Wlp2) * dis (bf16), gather ----
    gemm_mfma2_k<64, 40, false, true, true><<<mfmaGrid, b256, 0, stream>>>(
        hb, nullptr, nullptr, btl, dis, ub, N);
    gcn_gatM_k<<<gatNC, b256, 0, stream>>>((const ushort4*)ub, eoff, ecnt, esrc, dis, bias2, (float4*)d_out, N, nc4, npw);
}

// Round 3
// 433.234 us; speedup vs baseline: 1.1204x; 1.0916x over previous
//
#include <hip/hip_runtime.h>
#include <hip/hip_bf16.h>

// ---------------------------------------------------------------------------
// LPGCNHyperConvAblation, round 12: CSR front-end restructure.
//  - chunkhist_k: per-chunk histogram (1024 thr), stores chunkHist + gcnt.
//    Replaces bucket_count_k AND the recount inside the old bucket_place_k.
//  - place_k: loads chunk histogram from global, claims ranges, single
//    decode+scatter. PCHUNK=8192 (long bucket segments -> low write amp),
//    1024 threads/block (16 waves -> latency hiding).
// GEMMs (LDS-free MFMA), gathers, build_k unchanged from round 11.
// ---------------------------------------------------------------------------

typedef __attribute__((ext_vector_type(8))) short s16x8;
typedef __attribute__((ext_vector_type(4))) float f32x4;

__device__ __forceinline__ float ldf(const void* p, int f32, long long i) {
    if (f32) return ((const float*)p)[i];
    unsigned v = ((unsigned)((const unsigned short*)p)[i]) << 16;
    return __uint_as_float(v);
}

__device__ __forceinline__ int ldi(const int* __restrict__ w, int i64, long long i, int lim) {
    int v = i64 ? w[2 * i] : w[i];
    return ((unsigned)v < (unsigned)lim) ? v : 0;
}

__device__ __forceinline__ float b2f(unsigned short u) {
    return __uint_as_float(((unsigned)u) << 16);
}
__device__ __forceinline__ unsigned short f2b(float f) {
    __hip_bfloat16 h = __float2bfloat16(f);
    return *reinterpret_cast<unsigned short*>(&h);
}
__device__ __forceinline__ float4 b2f4(ushort4 u) {
    return make_float4(b2f(u.x), b2f(u.y), b2f(u.z), b2f(u.w));
}
__device__ __forceinline__ ushort4 f2b4(float4 v) {
    ushort4 u; u.x = f2b(v.x); u.y = f2b(v.y); u.z = f2b(v.z); u.w = f2b(v.w);
    return u;
}

// --- fused dtype detection ---------------------------------------------------
struct DPtrs { const void* p[13]; int n[13]; };

__global__ void detect_k(DPtrs dp, int* __restrict__ flags) {
    int b = blockIdx.x;
    __shared__ int cnt;
    if (threadIdx.x == 0) cnt = 0;
    __syncthreads();
    int c = 0;
    if (b < 11) {
        const unsigned short* u = (const unsigned short*)dp.p[b];
        int np = dp.n[b]; if (np > 2048) np = 2048;
        for (int i = threadIdx.x; i < np; i += blockDim.x) {
            unsigned e = (u[i] >> 7) & 0xFFu;
            if (e != 0u && (e < 90u || e > 160u)) c++;
        }
        atomicAdd(&cnt, c);
        __syncthreads();
        if (threadIdx.x == 0) flags[b] = (cnt * 8 > np) ? 1 : 0;
    } else {
        const int* w = (const int*)dp.p[b];
        int np = dp.n[b]; if (np > 1024) np = 1024;
        for (int i = threadIdx.x; i < np; i += blockDim.x)
            if (w[2 * i + 1] != 0) c++;
        atomicAdd(&cnt, c);
        __syncthreads();
        if (threadIdx.x == 0) flags[b] = (cnt == 0) ? 1 : 0;
    }
}

// --- CSR build (atomic-free pipeline) ----------------------------------------
struct Item { int b1; unsigned p1; int b2; unsigned p2; };

__device__ __forceinline__ Item decode(const int* __restrict__ ew, const int* __restrict__ hw,
                                       const int* __restrict__ FL, long long i,
                                       int E, int P, int N, int HE, int shN, int shH) {
    Item it; it.b2 = -1; it.p2 = 0;
    if (i < E) {
        int g = FL[11];
        int key = ldi(ew, g, (long long)E + i, N);
        int val = ldi(ew, g, i, N);
        it.b1 = key >> shN;
        it.p1 = ((unsigned)(key & ((1 << shN) - 1)) << 20) | (unsigned)val;
    } else {
        long long j = i - E;
        int g = FL[12];
        int nd = ldi(hw, g, j, N);
        int he = ldi(hw, g, (long long)P + j, HE);
        it.b1 = 256 + (nd >> shN);
        it.p1 = ((unsigned)(nd & ((1 << shN) - 1)) << 20) | (unsigned)he;
        it.b2 = 512 + (he >> shH);
        it.p2 = ((unsigned)(he & ((1 << shH) - 1)) << 20) | (unsigned)nd;
    }
    return it;
}

#define PCHUNK 8192
#define PTHREADS 1024

// per-chunk histogram -> chunkHist[chunk][768] + global gcnt
__global__ __launch_bounds__(PTHREADS)
void chunkhist_k(const int* __restrict__ ew, const int* __restrict__ hw,
                 const int* __restrict__ FL, int* __restrict__ gcnt,
                 int* __restrict__ chunkHist,
                 int E, int P, int N, int HE, int shN, int shH) {
    __shared__ int hist[768];
    int t = threadIdx.x;
    for (int b = t; b < 768; b += PTHREADS) hist[b] = 0;
    __syncthreads();
    long long T = (long long)E + P;
    long long start = (long long)blockIdx.x * PCHUNK;
    long long end = start + PCHUNK; if (end > T) end = T;
    for (long long i = start + t; i < end; i += PTHREADS) {
        Item it = decode(ew, hw, FL, i, E, P, N, HE, shN, shH);
        atomicAdd(&hist[it.b1], 1);
        if (it.b2 >= 0) atomicAdd(&hist[it.b2], 1);
    }
    __syncthreads();
    long long hbase = (long long)blockIdx.x * 768;
    for (int b = t; b < 768; b += PTHREADS) {
        int h = hist[b];
        chunkHist[hbase + b] = h;
        if (h) atomicAdd(&gcnt[b], h);
    }
}

__global__ void bucket_scan_k(const int* __restrict__ gcnt, int* __restrict__ bkOff,
                              int* __restrict__ gcur, int E, int P) {
    __shared__ int sh[256];
    int t = threadIdx.x;
    long long rbase[3] = {0, (long long)E, (long long)E + P};
    for (int c = 0; c < 3; c++) {
        int v = gcnt[c * 256 + t];
        sh[t] = v;
        __syncthreads();
        for (int o = 1; o < 256; o <<= 1) {
            int y = (t >= o) ? sh[t - o] : 0;
            __syncthreads();
            sh[t] += y;
            __syncthreads();
        }
        int excl = sh[t] - v;
        bkOff[c * 256 + t] = excl;
        gcur[c * 256 + t] = (int)(rbase[c] + excl);
        __syncthreads();
    }
}

// claim ranges from precomputed chunk histogram, single decode+scatter
__global__ __launch_bounds__(PTHREADS)
void place_k(const int* __restrict__ ew, const int* __restrict__ hw,
             const int* __restrict__ FL, int* __restrict__ gcur,
             const int* __restrict__ chunkHist, unsigned* __restrict__ pbuf,
             int E, int P, int N, int HE, int shN, int shH) {
    __shared__ int cur[768];
    long long T = (long long)E + P;
    long long start = (long long)blockIdx.x * PCHUNK;
    long long end = start + PCHUNK; if (end > T) end = T;
    int t = threadIdx.x;
    long long hbase = (long long)blockIdx.x * 768;
    for (int b = t; b < 768; b += PTHREADS) {
        int h = chunkHist[hbase + b];
        cur[b] = h ? atomicAdd(&gcur[b], h) : 0;
    }
    __syncthreads();
    for (long long i = start + t; i < end; i += PTHREADS) {
        Item it = decode(ew, hw, FL, i, E, P, N, HE, shN, shH);
        int s1 = atomicAdd(&cur[it.b1], 1);
        pbuf[s1] = it.p1;
        if (it.b2 >= 0) {
            int s2 = atomicAdd(&cur[it.b2], 1);
            pbuf[s2] = it.p2;
        }
    }
}

__global__ void build_k(const unsigned* __restrict__ pbuf,
                        const int* __restrict__ gcnt, const int* __restrict__ bkOff,
                        int* __restrict__ eoff, int* __restrict__ ecnt, int* __restrict__ esrc,
                        int* __restrict__ poffN, int* __restrict__ pcntN, int* __restrict__ pheL,
                        int* __restrict__ poffH, int* __restrict__ pcntH, int* __restrict__ pniL,
                        int E, int P, int N, int HE, int shN, int shH) {
    __shared__ int hist[512];
    __shared__ int offs[512];
    __shared__ int s2[256];
    int b = blockIdx.x, t = threadIdx.x;
    int csr = b >> 8, lb = b & 255;
    int sh    = (csr == 2) ? shH : shN;
    int nkeys = (csr == 2) ? HE : N;
    int span = 1 << sh;
    int keyBase = lb << sh;
    if (keyBase >= nkeys) return;
    int keyEnd = keyBase + span; if (keyEnd > nkeys) keyEnd = nkeys;
    int cnt = gcnt[b];
    long long rbase = (csr == 0) ? 0 : ((csr == 1) ? (long long)E : (long long)E + P);
    long long pstart = rbase + bkOff[b];
    int lstBase = bkOff[b];
    int* off  = (csr == 0) ? eoff : ((csr == 1) ? poffN : poffH);
    int* cntA = (csr == 0) ? ecnt : ((csr == 1) ? pcntN : pcntH);
    int* lst  = (csr == 0) ? esrc : ((csr == 1) ? pheL : pniL);

    for (int k = t; k < 512; k += 256) hist[k] = 0;
    __syncthreads();
    for (int i = t; i < cnt; i += 256)
        atomicAdd(&hist[pbuf[pstart + i] >> 20], 1);
    __syncthreads();
    int a0 = hist[2 * t], a1 = hist[2 * t + 1];
    s2[t] = a0 + a1;
    __syncthreads();
    for (int o = 1; o < 256; o <<= 1) {
        int y = (t >= o) ? s2[t - o] : 0;
        __syncthreads();
        s2[t] += y;
        __syncthreads();
    }
    int excl = s2[t] - (a0 + a1);
    offs[2 * t] = excl;
    offs[2 * t + 1] = excl + a0;
    __syncthreads();
    for (int k = keyBase + t; k < keyEnd; k += 256) {
        off[k]  = lstBase + offs[k - keyBase];
        cntA[k] = hist[k - keyBase];
    }
    __syncthreads();
    for (int i = t; i < cnt; i += 256) {
        unsigned u = pbuf[pstart + i];
        int lk = u >> 20;
        int slot = atomicAdd(&offs[lk], 1);
        lst[lstBase + slot] = (int)(u & 0xFFFFFu);
    }
}

// --- fused norm factors ------------------------------------------------------
__global__ void norms_k(const int* __restrict__ ecnt, const int* __restrict__ pcntN,
                        const int* __restrict__ pcntH, float* __restrict__ dis,
                        float* __restrict__ Dinv, float* __restrict__ Binv, int N, int HE) {
    int i = blockIdx.x * blockDim.x + threadIdx.x;
    if (i < N) dis[i] = rsqrtf((float)(ecnt[i] + 1));
    else if (i < 2 * N) { int c = pcntN[i - N]; Dinv[i - N] = c ? (1.f / (float)c) : 0.f; }
    else if (i < 2 * N + HE) { int c = pcntH[i - 2 * N]; Binv[i - 2 * N] = c ? (1.f / (float)c) : 0.f; }
}

// --- Wlp2 = W_c2 @ W_lp, bias2 = b_c2 @ W_lp + b_lp  (LDS-staged) ------------
__global__ void wlp2_k(const void* Wc2, const int* fWc2, const void* Wlp, const int* fWlp,
                       const void* bc2, const int* fbc2, const void* blp, const int* fblp,
                       float* __restrict__ Wlp2, float* __restrict__ bias2, int NC) {
    extern __shared__ float sm[];
    float* sW2 = sm;                 // 64*NC  (W_c2)
    float* sLP = sm + 64 * NC;       // NC*NC  (W_lp)
    int t = threadIdx.x;
    int fw2 = fWc2[0], flp = fWlp[0];
    for (int e = t; e < 64 * NC; e += blockDim.x) sW2[e] = ldf(Wc2, fw2, e);
    for (int e = t; e < NC * NC; e += blockDim.x) sLP[e] = ldf(Wlp, flp, e);
    __syncthreads();
    for (int e = t; e < 64 * NC; e += blockDim.x) {
        int r = e / NC, c = e % NC;
        float s = 0.f;
        for (int k = 0; k < NC; k++) s = fmaf(sW2[r * NC + k], sLP[k * NC + c], s);
        Wlp2[e] = s;
    }
    if (t < NC) {
        float s = ldf(blp, fblp[0], t);
        int fb2 = fbc2[0];
        for (int k = 0; k < NC; k++) s = fmaf(ldf(bc2, fb2, k), sLP[k * NC + t], s);
        bias2[t] = s;
    }
}

// --- B prep: Bt[m][k] = bf16(B[k][m]), zero-pad m in [M, Mp) -----------------
struct BP { const void* B; const int* fB; int K; int M; int Mp; unsigned short* out; };

__global__ void bprep_k(BP p0, BP p1, BP p2, BP p3) {
    BP p = (blockIdx.x == 0) ? p0 : (blockIdx.x == 1) ? p1 : (blockIdx.x == 2) ? p2 : p3;
    int fb = p.fB ? p.fB[0] : 1;
    int tot = p.Mp * p.K;
    for (int e = threadIdx.x; e < tot; e += blockDim.x) {
        int m = e / p.K, k = e - m * p.K;
        float v = (m < p.M) ? ldf(p.B, fb, (long long)k * p.M + m) : 0.f;
        p.out[e] = f2b(v);
    }
}

// --- bf16 gathers: 4 rows/wave, 16 lanes x ushort4 (D=64) --------------------
__global__ void gat_n2e_k(const ushort4* __restrict__ xw, const int* __restrict__ off,
                          const int* __restrict__ cnt, const int* __restrict__ lst,
                          const float* __restrict__ Binv, ushort4* __restrict__ ef, int HE) {
    int idx = blockIdx.x * blockDim.x + threadIdx.x;
    int e = idx >> 4, l = idx & 15;
    if (e >= HE) return;
    int o = off[e], c = cnt[e];
    float4 a = make_float4(0.f, 0.f, 0.f, 0.f);
    int j = 0;
    for (; j + 4 <= c; j += 4) {
        int s0 = lst[o + j], s1 = lst[o + j + 1], s2 = lst[o + j + 2], s3 = lst[o + j + 3];
        float4 v0 = b2f4(xw[((long long)s0 << 4) + l]);
        float4 v1 = b2f4(xw[((long long)s1 << 4) + l]);
        float4 v2 = b2f4(xw[((long long)s2 << 4) + l]);
        float4 v3 = b2f4(xw[((long long)s3 << 4) + l]);
        a.x += (v0.x + v1.x) + (v2.x + v3.x);
        a.y += (v0.y + v1.y) + (v2.y + v3.y);
        a.z += (v0.z + v1.z) + (v2.z + v3.z);
        a.w += (v0.w + v1.w) + (v2.w + v3.w);
    }
    for (; j < c; j++) {
        float4 v = b2f4(xw[((long long)lst[o + j] << 4) + l]);
        a.x += v.x; a.y += v.y; a.z += v.z; a.w += v.w;
    }
    float bi = Binv[e];
    a.x *= bi; a.y *= bi; a.z *= bi; a.w *= bi;
    ef[((long long)e << 4) + l] = f2b4(a);
}

// hyperedge -> node: out = Dinv*sum + bias (+relu), bf16 out
template <bool RELU>
__global__ void gat_e2n_k(const ushort4* __restrict__ ef, const int* __restrict__ off,
                          const int* __restrict__ cnt, const int* __restrict__ lst,
                          const float* __restrict__ Dinv, const void* __restrict__ bias,
                          const int* __restrict__ fb, ushort4* __restrict__ out, int N) {
    int idx = blockIdx.x * blockDim.x + threadIdx.x;
    int w = idx >> 4, l = idx & 15;
    if (w >= N) return;
    int o = off[w], c = cnt[w];
    float4 a = make_float4(0.f, 0.f, 0.f, 0.f);
    int j = 0;
    for (; j + 4 <= c; j += 4) {
        int s0 = lst[o + j], s1 = lst[o + j + 1], s2 = lst[o + j + 2], s3 = lst[o + j + 3];
        float4 v0 = b2f4(ef[((long long)s0 << 4) + l]);
        float4 v1 = b2f4(ef[((long long)s1 << 4) + l]);
        float4 v2 = b2f4(ef[((long long)s2 << 4) + l]);
        float4 v3 = b2f4(ef[((long long)s3 << 4) + l]);
        a.x += (v0.x + v1.x) + (v2.x + v3.x);
        a.y += (v0.y + v1.y) + (v2.y + v3.y);
        a.z += (v0.z + v1.z) + (v2.z + v3.z);
        a.w += (v0.w + v1.w) + (v2.w + v3.w);
    }
    for (; j < c; j++) {
        float4 v = b2f4(ef[((long long)lst[o + j] << 4) + l]);
        a.x += v.x; a.y += v.y; a.z += v.z; a.w += v.w;
    }
    float di = Dinv[w];
    int fbv = fb[0];
    float4 b = make_float4(ldf(bias, fbv, 4 * l), ldf(bias, fbv, 4 * l + 1),
                           ldf(bias, fbv, 4 * l + 2), ldf(bias, fbv, 4 * l + 3));
    a.x = a.x * di + b.x; a.y = a.y * di + b.y;
    a.z = a.z * di + b.z; a.w = a.w * di + b.w;
    if (RELU) {
        a.x = fmaxf(a.x, 0.f); a.y = fmaxf(a.y, 0.f);
        a.z = fmaxf(a.z, 0.f); a.w = fmaxf(a.w, 0.f);
    }
    out[((long long)w << 4) + l] = f2b4(a);
}

// GCN aggregation on pre-scaled bf16 y, bf16 out
template <bool RELU>
__global__ void gcn_gat_k(const ushort4* __restrict__ y, const int* __restrict__ off,
                          const int* __restrict__ cnt, const int* __restrict__ lst,
                          const float* __restrict__ dis, const void* __restrict__ bias,
                          const int* __restrict__ fb, ushort4* __restrict__ out, int N) {
    int idx = blockIdx.x * blockDim.x + threadIdx.x;
    int w = idx >> 4, l = idx & 15;
    if (w >= N) return;
    int o = off[w], c = cnt[w];
    float4 a = b2f4(y[((long long)w << 4) + l]);
    int j = 0;
    for (; j + 4 <= c; j += 4) {
        int s0 = lst[o + j], s1 = lst[o + j + 1], s2 = lst[o + j + 2], s3 = lst[o + j + 3];
        float4 v0 = b2f4(y[((long long)s0 << 4) + l]);
        float4 v1 = b2f4(y[((long long)s1 << 4) + l]);
        float4 v2 = b2f4(y[((long long)s2 << 4) + l]);
        float4 v3 = b2f4(y[((long long)s3 << 4) + l]);
        a.x += (v0.x + v1.x) + (v2.x + v3.x);
        a.y += (v0.y + v1.y) + (v2.y + v3.y);
        a.z += (v0.z + v1.z) + (v2.z + v3.z);
        a.w += (v0.w + v1.w) + (v2.w + v3.w);
    }
    for (; j < c; j++) {
        float4 v = b2f4(y[((long long)lst[o + j] << 4) + l]);
        a.x += v.x; a.y += v.y; a.z += v.z; a.w += v.w;
    }
    float dd = dis[w];
    int fbv = fb[0];
    float4 b = make_float4(ldf(bias, fbv, 4 * l), ldf(bias, fbv, 4 * l + 1),
                           ldf(bias, fbv, 4 * l + 2), ldf(bias, fbv, 4 * l + 3));
    a.x = a.x * dd + b.x; a.y = a.y * dd + b.y;
    a.z = a.z * dd + b.z; a.w = a.w * dd + b.w;
    if (RELU) {
        a.x = fmaxf(a.x, 0.f); a.y = fmaxf(a.y, 0.f);
        a.z = fmaxf(a.z, 0.f); a.w = fmaxf(a.w, 0.f);
    }
    out[((long long)w << 4) + l] = f2b4(a);
}

// final GCN aggregation over bf16 y2 (M=NC), writes d_out fp32
__global__ void gcn_gatM_k(const ushort4* __restrict__ y2, const int* __restrict__ off,
                           const int* __restrict__ cnt, const int* __restrict__ lst,
                           const float* __restrict__ dis, const float* __restrict__ bias2,
                           float4* __restrict__ out4, int N, int nc4, int npw) {
    int idx = blockIdx.x * blockDim.x + threadIdx.x;
    int wave = idx >> 6, l64 = idx & 63;
    int grp = l64 / 10, li = l64 - grp * 10;
    if (nc4 != 10) { grp = l64 / nc4; li = l64 - grp * nc4; }
    int w = wave * npw + grp;
    if (grp >= npw || w >= N) return;
    int o = off[w], c = cnt[w];
    float4 a = b2f4(y2[(long long)w * nc4 + li]);
    int j = 0;
    for (; j + 4 <= c; j += 4) {
        int s0 = lst[o + j], s1 = lst[o + j + 1], s2 = lst[o + j + 2], s3 = lst[o + j + 3];
        float4 v0 = b2f4(y2[(long long)s0 * nc4 + li]);
        float4 v1 = b2f4(y2[(long long)s1 * nc4 + li]);
        float4 v2 = b2f4(y2[(long long)s2 * nc4 + li]);
        float4 v3 = b2f4(y2[(long long)s3 * nc4 + li]);
        a.x += (v0.x + v1.x) + (v2.x + v3.x);
        a.y += (v0.y + v1.y) + (v2.y + v3.y);
        a.z += (v0.z + v1.z) + (v2.z + v3.z);
        a.w += (v0.w + v1.w) + (v2.w + v3.w);
    }
    for (; j < c; j++) {
        float4 v = b2f4(y2[(long long)lst[o + j] * nc4 + li]);
        a.x += v.x; a.y += v.y; a.z += v.z; a.w += v.w;
    }
    float dd = dis[w];
    float4 b = *(const float4*)&bias2[4 * li];
    a.x = a.x * dd + b.x; a.y = a.y * dd + b.y;
    a.z = a.z * dd + b.z; a.w = a.w * dd + b.w;
    out4[(long long)w * nc4 + li] = a;
}

// --- load 8 source elements as bf16 (fp32->cvt or bf16 passthrough) ----------
__device__ __forceinline__ s16x8 load8bf(const void* A, int af, long long base) {
    s16x8 o;
    if (af) {
        float4 v0 = *(const float4*)((const float*)A + base);
        float4 v1 = *(const float4*)((const float*)A + base + 4);
        o[0] = (short)f2b(v0.x); o[1] = (short)f2b(v0.y);
        o[2] = (short)f2b(v0.z); o[3] = (short)f2b(v0.w);
        o[4] = (short)f2b(v1.x); o[5] = (short)f2b(v1.y);
        o[6] = (short)f2b(v1.z); o[7] = (short)f2b(v1.w);
    } else {
        o = *(const s16x8*)&((const unsigned short*)A)[base];
    }
    return o;
}

// --- LDS-free MFMA GEMM: one wave = 32 rows x MM cols, B^T bf16 from global --
// Fragment layouts (gfx950, verified m89/m92): A lane=row(l&15),k=8*(l>>4)+j;
// B lane=col(l&15),k=8*(l>>4)+j; D col=l&15,row=(l>>4)*4+i.
template <int KK, int MM, bool CATMODE, bool ABF16, bool SCALE>
__global__ __launch_bounds__(256)
void gemm_mfma2_k(const void* __restrict__ A, const int* __restrict__ fA,
                  const unsigned short* __restrict__ A2,
                  const unsigned short* __restrict__ Bt,
                  const float* __restrict__ dscale,
                  unsigned short* __restrict__ C, int NR) {
    constexpr int MT = (MM + 15) / 16;
    static_assert(KK % 32 == 0, "K must be multiple of 32");

    const int t = threadIdx.x;
    const int wid = t >> 6, lane = t & 63;
    const long long r0 = ((long long)blockIdx.x * 4 + wid) * 32;
    if (r0 >= NR) return;

    const int af = fA ? fA[0] : 1;
    const int arow = lane & 15;
    const int kgrp = lane >> 4;
    long long ra = r0 + arow;      if (ra > NR - 1) ra = NR - 1;
    long long rb = r0 + 16 + arow; if (rb > NR - 1) rb = NR - 1;

    f32x4 acc0[MT] = {};
    f32x4 acc1[MT] = {};
#pragma unroll
    for (int kc = 0; kc < KK; kc += 32) {
        const int kb = kc + kgrp * 8;
        s16x8 a0, a1;
        if constexpr (CATMODE) {
            if (kc < 128) {   // kb in [kc, kc+24] < 128 since kc <= 96
                a0 = load8bf(A, af, ra * 128 + kb);
                a1 = load8bf(A, af, rb * 128 + kb);
            } else {
                a0 = *(const s16x8*)&A2[ra * 64 + (kb - 128)];
                a1 = *(const s16x8*)&A2[rb * 64 + (kb - 128)];
            }
        } else if constexpr (ABF16) {
            a0 = *(const s16x8*)&((const unsigned short*)A)[ra * KK + kb];
            a1 = *(const s16x8*)&((const unsigned short*)A)[rb * KK + kb];
        } else {
            a0 = load8bf(A, af, ra * (long long)KK + kb);
            a1 = load8bf(A, af, rb * (long long)KK + kb);
        }
#pragma unroll
        for (int m = 0; m < MT; m++) {
            s16x8 b = *(const s16x8*)&Bt[(m * 16 + arow) * KK + kb];
            acc0[m] = __builtin_amdgcn_mfma_f32_16x16x32_bf16(a0, b, acc0[m], 0, 0, 0);
            acc1[m] = __builtin_amdgcn_mfma_f32_16x16x32_bf16(a1, b, acc1[m], 0, 0, 0);
        }
    }

    // ---- store: D col=lane&15, row=(lane>>4)*4+i ----
    const int col0 = lane & 15;
    const int rsub = (lane >> 4) * 4;
#pragma unroll
    for (int h = 0; h < 2; h++) {
#pragma unroll
        for (int i = 0; i < 4; i++) {
            long long r = r0 + h * 16 + rsub + i;
            if (r < NR) {
                float s = SCALE ? dscale[r] : 1.f;
#pragma unroll
                for (int m = 0; m < MT; m++) {
                    int col = m * 16 + col0;
                    float val = h ? acc1[m][i] : acc0[m][i];
                    if (MT * 16 == MM || col < MM)
                        C[r * MM + col] = f2b(val * s);
                }
            }
        }
    }
}

static inline dim3 g1d(long long n, int b) { return dim3((unsigned)((n + b - 1) / b)); }
static inline int imin(int a, int b) { return a < b ? a : b; }

extern "C" void kernel_launch(void* const* d_in, const int* in_sizes, int n_in,
                              void* d_out, int out_size, void* d_ws, size_t ws_size,
                              hipStream_t stream) {
    const int N  = in_sizes[0] / 128;   // 100000
    const int E  = in_sizes[1] / 2;     // 1600000
    const int P  = in_sizes[2] / 2;     // 800000
    const int HE = 20000;
    const int NC = in_sizes[9] / 64;    // 40
    const int nc4 = NC / 4;             // 10
    const int npw = 64 / nc4;           // 6

    const void* x    = d_in[0];
    const int*  ew   = (const int*)d_in[1];
    const int*  hw   = (const int*)d_in[2];
    const void* W_h1 = d_in[3];
    const void* b_h1 = d_in[4];
    const void* W_h2 = d_in[5];
    const void* b_h2 = d_in[6];
    const void* W_c1 = d_in[7];
    const void* b_c1 = d_in[8];
    const void* W_c2 = d_in[9];
    const void* b_c2 = d_in[10];
    const void* W_lp = d_in[11];
    const void* b_lp = d_in[12];

    int shN = 0; while (((N - 1) >> shN) >= 256) shN++;   // 9
    int shH = 0; while (((HE - 1) >> shH) >= 256) shH++;  // 7

    long long T = (long long)E + P;
    int nChunks = (int)((T + PCHUNK - 1) / PCHUNK);

    // ---- workspace ----
    char* wp = (char*)d_ws;
    auto allocF = [&](size_t n) { float* p = (float*)wp; wp += n * 4; return p; };
    auto allocI = [&](size_t n) { int* p = (int*)wp; wp += n * 4; return p; };
    unsigned short* ub  = (unsigned short*)allocF((size_t)N * 32);   // bf16 N*64 (GEMM out)
    unsigned short* hb  = (unsigned short*)allocF((size_t)N * 32);   // bf16 N*64 (gather out)
    unsigned short* efb = (unsigned short*)allocF((size_t)HE * 32);  // bf16 HE*64
    float* dis   = allocF(N);
    float* Dinv  = allocF(N);
    float* Binv  = allocF(HE);
    float* Wlp2  = allocF((size_t)64 * NC);
    float* bias2 = allocF(NC);
    unsigned short* bt1 = (unsigned short*)allocF((size_t)64 * 128 / 2);  // W_h1^T bf16
    unsigned short* bt2 = (unsigned short*)allocF((size_t)64 * 64 / 2);   // W_h2^T bf16
    unsigned short* btc = (unsigned short*)allocF((size_t)64 * 192 / 2);  // W_c1^T bf16
    unsigned short* btl = (unsigned short*)allocF((size_t)48 * 64 / 2);   // Wlp2^T bf16
    int* ecnt  = allocI(N);
    int* pcntN = allocI(N);
    int* pcntH = allocI(HE);
    int* eoff  = allocI(N);
    int* poffN = allocI(N);
    int* poffH = allocI(HE);
    int* esrc  = allocI(E);
    int* pheL  = allocI(P);
    int* pniL  = allocI(P);
    int* gBkt  = allocI(768);
    int* bkOff = allocI(768);
    int* gcur  = allocI(768);
    int* FL    = allocI(16);
    int* chunkHist = allocI((size_t)nChunks * 768);
    unsigned* pbuf = (unsigned*)allocI((size_t)E + 2 * (size_t)P);

    dim3 b256(256), b1024(PTHREADS), d1(1);

    // ---- dtype detection ----
    DPtrs dp;
    const void* farr[11] = {x, W_h1, b_h1, W_h2, b_h2, W_c1, b_c1, W_c2, b_c2, W_lp, b_lp};
    const int   fsz[11]  = {in_sizes[0], in_sizes[3], in_sizes[4], in_sizes[5], in_sizes[6],
                            in_sizes[7], in_sizes[8], in_sizes[9], in_sizes[10], in_sizes[11],
                            in_sizes[12]};
    for (int i = 0; i < 11; ++i) { dp.p[i] = farr[i]; dp.n[i] = fsz[i]; }
    dp.p[11] = ew; dp.n[11] = imin(E, 1024);
    dp.p[12] = hw; dp.n[12] = imin(P, 1024);
    detect_k<<<dim3(13), b256, 0, stream>>>(dp, FL);
    const int* fX   = FL + 0;
    const int* fWh1 = FL + 1,  *fbh1 = FL + 2;
    const int* fWh2 = FL + 3,  *fbh2 = FL + 4;
    const int* fWc1 = FL + 5,  *fbc1 = FL + 6;
    const int* fWc2 = FL + 7,  *fbc2 = FL + 8;
    const int* fWlp = FL + 9,  *fblp = FL + 10;

    // ---- CSR build ----
    hipMemsetAsync(gBkt, 0, 768 * 4, stream);
    chunkhist_k<<<dim3(nChunks), b1024, 0, stream>>>(ew, hw, FL, gBkt, chunkHist,
                                                     E, P, N, HE, shN, shH);
    bucket_scan_k<<<d1, b256, 0, stream>>>(gBkt, bkOff, gcur, E, P);
    place_k<<<dim3(nChunks), b1024, 0, stream>>>(ew, hw, FL, gcur, chunkHist, pbuf,
                                                 E, P, N, HE, shN, shH);
    build_k<<<dim3(768), b256, 0, stream>>>(pbuf, gBkt, bkOff,
                                            eoff, ecnt, esrc,
                                            poffN, pcntN, pheL,
                                            poffH, pcntH, pniL,
                                            E, P, N, HE, shN, shH);

    // ---- norms + fused tail weights + B transposes ----
    norms_k<<<g1d(2 * N + HE, 256), b256, 0, stream>>>(ecnt, pcntN, pcntH, dis, Dinv, Binv, N, HE);
    wlp2_k<<<d1, b256, (64 * NC + NC * NC) * 4, stream>>>(
        W_c2, fWc2, W_lp, fWlp, b_c2, fbc2, b_lp, fblp, Wlp2, bias2, NC);
    {
        BP p0 = {W_h1, fWh1, 128, 64, 64, bt1};
        BP p1 = {W_h2, fWh2,  64, 64, 64, bt2};
        BP p2 = {W_c1, fWc1, 192, 64, 64, btc};
        BP p3 = {Wlp2, nullptr, 64, NC, 48, btl};
        bprep_k<<<dim3(4), b256, 0, stream>>>(p0, p1, p2, p3);
    }

    const dim3 mfmaGrid((N + 127) / 128);
    const dim3 gatN16(g1d((long long)N * 16, 256));
    const dim3 gatH16(g1d((long long)HE * 16, 256));
    const dim3 gatNC(g1d((long long)((N + npw - 1) / npw) * 64, 256));

    // ---- hyperconv 1 ----
    gemm_mfma2_k<128, 64, false, false, false><<<mfmaGrid, b256, 0, stream>>>(
        x, fX, nullptr, bt1, nullptr, ub, N);
    gat_n2e_k<<<gatH16, b256, 0, stream>>>((const ushort4*)ub, poffH, pcntH, pniL, Binv, (ushort4*)efb, HE);
    gat_e2n_k<true><<<gatN16, b256, 0, stream>>>((const ushort4*)efb, poffN, pcntN, pheL, Dinv, b_h1, fbh1, (ushort4*)hb, N);

    // ---- hyperconv 2 ----
    gemm_mfma2_k<64, 64, false, true, false><<<mfmaGrid, b256, 0, stream>>>(
        hb, nullptr, nullptr, bt2, nullptr, ub, N);
    gat_n2e_k<<<gatH16, b256, 0, stream>>>((const ushort4*)ub, poffH, pcntH, pniL, Binv, (ushort4*)efb, HE);
    gat_e2n_k<false><<<gatN16, b256, 0, stream>>>((const ushort4*)efb, poffN, pcntN, pheL, Dinv, b_h2, fbh2, (ushort4*)hb, N);
    // hb = x_hyper (bf16)

    // ---- gcn 1: y = ([x|x_hyper] @ W_c1) * dis (bf16), then gather ----
    gemm_mfma2_k<192, 64, true, false, true><<<mfmaGrid, b256, 0, stream>>>(
        x, fX, hb, btc, dis, ub, N);
    gcn_gat_k<true><<<gatN16, b256, 0, stream>>>((const ushort4*)ub, eoff, ecnt, esrc, dis, b_c1, fbc1, (ushort4*)hb, N);

    // ---- gcn 2 + final linear fused: y2 = (hb @ Wlp2) * dis (bf16), gather ----
    gemm_mfma2_k<64, 40, false, true, true><<<mfmaGrid, b256, 0, stream>>>(
        hb, nullptr, nullptr, btl, dis, ub, N);
    gcn_gatM_k<<<gatNC, b256, 0, stream>>>((const ushort4*)ub, eoff, ecnt, esrc, dis, bias2, (float4*)d_out, N, nc4, npw);
}

// Round 4
// 409.047 us; speedup vs baseline: 1.1866x; 1.0591x over previous
//
#include <hip/hip_runtime.h>
#include <hip/hip_bf16.h>

// ---------------------------------------------------------------------------
// LPGCNHyperConvAblation, round 13:
//  - gathers rewidened: 8 lanes x 16B (s16x8) per row, halves VMEM ops and
//    redundant index loads; gcn_gatM uses 5 lanes/row (NC=40), 12 rows/wave.
//  - norms fused into build_k (dis/Dinv/Binv written from the LDS hist).
//  - wlp2_k + bprep_k merged into prep_k; fp32 Wlp2 intermediate dropped
//    (wlp2 block emits bf16-transposed btl directly).
// CSR front-end (chunkhist/scan/place) and MFMA GEMMs unchanged from r12.
// ---------------------------------------------------------------------------

typedef __attribute__((ext_vector_type(8))) short s16x8;
typedef __attribute__((ext_vector_type(4))) float f32x4;
typedef __attribute__((ext_vector_type(8))) float f32x8;

__device__ __forceinline__ float ldf(const void* p, int f32, long long i) {
    if (f32) return ((const float*)p)[i];
    unsigned v = ((unsigned)((const unsigned short*)p)[i]) << 16;
    return __uint_as_float(v);
}

__device__ __forceinline__ int ldi(const int* __restrict__ w, int i64, long long i, int lim) {
    int v = i64 ? w[2 * i] : w[i];
    return ((unsigned)v < (unsigned)lim) ? v : 0;
}

__device__ __forceinline__ float b2f(unsigned short u) {
    return __uint_as_float(((unsigned)u) << 16);
}
__device__ __forceinline__ unsigned short f2b(float f) {
    __hip_bfloat16 h = __float2bfloat16(f);
    return *reinterpret_cast<unsigned short*>(&h);
}
__device__ __forceinline__ f32x8 b2f8(s16x8 u) {
    f32x8 r;
#pragma unroll
    for (int q = 0; q < 8; q++) r[q] = b2f((unsigned short)u[q]);
    return r;
}
__device__ __forceinline__ s16x8 f2b8(f32x8 v) {
    s16x8 r;
#pragma unroll
    for (int q = 0; q < 8; q++) r[q] = (short)f2b(v[q]);
    return r;
}

// --- fused dtype detection ---------------------------------------------------
struct DPtrs { const void* p[13]; int n[13]; };

__global__ void detect_k(DPtrs dp, int* __restrict__ flags) {
    int b = blockIdx.x;
    __shared__ int cnt;
    if (threadIdx.x == 0) cnt = 0;
    __syncthreads();
    int c = 0;
    if (b < 11) {
        const unsigned short* u = (const unsigned short*)dp.p[b];
        int np = dp.n[b]; if (np > 2048) np = 2048;
        for (int i = threadIdx.x; i < np; i += blockDim.x) {
            unsigned e = (u[i] >> 7) & 0xFFu;
            if (e != 0u && (e < 90u || e > 160u)) c++;
        }
        atomicAdd(&cnt, c);
        __syncthreads();
        if (threadIdx.x == 0) flags[b] = (cnt * 8 > np) ? 1 : 0;
    } else {
        const int* w = (const int*)dp.p[b];
        int np = dp.n[b]; if (np > 1024) np = 1024;
        for (int i = threadIdx.x; i < np; i += blockDim.x)
            if (w[2 * i + 1] != 0) c++;
        atomicAdd(&cnt, c);
        __syncthreads();
        if (threadIdx.x == 0) flags[b] = (cnt == 0) ? 1 : 0;
    }
}

// --- CSR build (atomic-free pipeline) ----------------------------------------
struct Item { int b1; unsigned p1; int b2; unsigned p2; };

__device__ __forceinline__ Item decode(const int* __restrict__ ew, const int* __restrict__ hw,
                                       const int* __restrict__ FL, long long i,
                                       int E, int P, int N, int HE, int shN, int shH) {
    Item it; it.b2 = -1; it.p2 = 0;
    if (i < E) {
        int g = FL[11];
        int key = ldi(ew, g, (long long)E + i, N);
        int val = ldi(ew, g, i, N);
        it.b1 = key >> shN;
        it.p1 = ((unsigned)(key & ((1 << shN) - 1)) << 20) | (unsigned)val;
    } else {
        long long j = i - E;
        int g = FL[12];
        int nd = ldi(hw, g, j, N);
        int he = ldi(hw, g, (long long)P + j, HE);
        it.b1 = 256 + (nd >> shN);
        it.p1 = ((unsigned)(nd & ((1 << shN) - 1)) << 20) | (unsigned)he;
        it.b2 = 512 + (he >> shH);
        it.p2 = ((unsigned)(he & ((1 << shH) - 1)) << 20) | (unsigned)nd;
    }
    return it;
}

#define PCHUNK 8192
#define PTHREADS 1024

// per-chunk histogram -> chunkHist[chunk][768] + global gcnt
__global__ __launch_bounds__(PTHREADS)
void chunkhist_k(const int* __restrict__ ew, const int* __restrict__ hw,
                 const int* __restrict__ FL, int* __restrict__ gcnt,
                 int* __restrict__ chunkHist,
                 int E, int P, int N, int HE, int shN, int shH) {
    __shared__ int hist[768];
    int t = threadIdx.x;
    for (int b = t; b < 768; b += PTHREADS) hist[b] = 0;
    __syncthreads();
    long long T = (long long)E + P;
    long long start = (long long)blockIdx.x * PCHUNK;
    long long end = start + PCHUNK; if (end > T) end = T;
    for (long long i = start + t; i < end; i += PTHREADS) {
        Item it = decode(ew, hw, FL, i, E, P, N, HE, shN, shH);
        atomicAdd(&hist[it.b1], 1);
        if (it.b2 >= 0) atomicAdd(&hist[it.b2], 1);
    }
    __syncthreads();
    long long hbase = (long long)blockIdx.x * 768;
    for (int b = t; b < 768; b += PTHREADS) {
        int h = hist[b];
        chunkHist[hbase + b] = h;
        if (h) atomicAdd(&gcnt[b], h);
    }
}

__global__ void bucket_scan_k(const int* __restrict__ gcnt, int* __restrict__ bkOff,
                              int* __restrict__ gcur, int E, int P) {
    __shared__ int sh[256];
    int t = threadIdx.x;
    long long rbase[3] = {0, (long long)E, (long long)E + P};
    for (int c = 0; c < 3; c++) {
        int v = gcnt[c * 256 + t];
        sh[t] = v;
        __syncthreads();
        for (int o = 1; o < 256; o <<= 1) {
            int y = (t >= o) ? sh[t - o] : 0;
            __syncthreads();
            sh[t] += y;
            __syncthreads();
        }
        int excl = sh[t] - v;
        bkOff[c * 256 + t] = excl;
        gcur[c * 256 + t] = (int)(rbase[c] + excl);
        __syncthreads();
    }
}

// claim ranges from precomputed chunk histogram, single decode+scatter
__global__ __launch_bounds__(PTHREADS)
void place_k(const int* __restrict__ ew, const int* __restrict__ hw,
             const int* __restrict__ FL, int* __restrict__ gcur,
             const int* __restrict__ chunkHist, unsigned* __restrict__ pbuf,
             int E, int P, int N, int HE, int shN, int shH) {
    __shared__ int cur[768];
    long long T = (long long)E + P;
    long long start = (long long)blockIdx.x * PCHUNK;
    long long end = start + PCHUNK; if (end > T) end = T;
    int t = threadIdx.x;
    long long hbase = (long long)blockIdx.x * 768;
    for (int b = t; b < 768; b += PTHREADS) {
        int h = chunkHist[hbase + b];
        cur[b] = h ? atomicAdd(&gcur[b], h) : 0;
    }
    __syncthreads();
    for (long long i = start + t; i < end; i += PTHREADS) {
        Item it = decode(ew, hw, FL, i, E, P, N, HE, shN, shH);
        int s1 = atomicAdd(&cur[it.b1], 1);
        pbuf[s1] = it.p1;
        if (it.b2 >= 0) {
            int s2 = atomicAdd(&cur[it.b2], 1);
            pbuf[s2] = it.p2;
        }
    }
}

// build CSR lists + fused norm factors (dis/Dinv/Binv from LDS hist)
__global__ void build_k(const unsigned* __restrict__ pbuf,
                        const int* __restrict__ gcnt, const int* __restrict__ bkOff,
                        int* __restrict__ eoff, int* __restrict__ ecnt, int* __restrict__ esrc,
                        int* __restrict__ poffN, int* __restrict__ pcntN, int* __restrict__ pheL,
                        int* __restrict__ poffH, int* __restrict__ pcntH, int* __restrict__ pniL,
                        float* __restrict__ dis, float* __restrict__ Dinv, float* __restrict__ Binv,
                        int E, int P, int N, int HE, int shN, int shH) {
    __shared__ int hist[512];
    __shared__ int offs[512];
    __shared__ int s2[256];
    int b = blockIdx.x, t = threadIdx.x;
    int csr = b >> 8, lb = b & 255;
    int sh    = (csr == 2) ? shH : shN;
    int nkeys = (csr == 2) ? HE : N;
    int span = 1 << sh;
    int keyBase = lb << sh;
    if (keyBase >= nkeys) return;
    int keyEnd = keyBase + span; if (keyEnd > nkeys) keyEnd = nkeys;
    int cnt = gcnt[b];
    long long rbase = (csr == 0) ? 0 : ((csr == 1) ? (long long)E : (long long)E + P);
    long long pstart = rbase + bkOff[b];
    int lstBase = bkOff[b];
    int* off  = (csr == 0) ? eoff : ((csr == 1) ? poffN : poffH);
    int* cntA = (csr == 0) ? ecnt : ((csr == 1) ? pcntN : pcntH);
    int* lst  = (csr == 0) ? esrc : ((csr == 1) ? pheL : pniL);

    for (int k = t; k < 512; k += 256) hist[k] = 0;
    __syncthreads();
    for (int i = t; i < cnt; i += 256)
        atomicAdd(&hist[pbuf[pstart + i] >> 20], 1);
    __syncthreads();
    int a0 = hist[2 * t], a1 = hist[2 * t + 1];
    s2[t] = a0 + a1;
    __syncthreads();
    for (int o = 1; o < 256; o <<= 1) {
        int y = (t >= o) ? s2[t - o] : 0;
        __syncthreads();
        s2[t] += y;
        __syncthreads();
    }
    int excl = s2[t] - (a0 + a1);
    offs[2 * t] = excl;
    offs[2 * t + 1] = excl + a0;
    __syncthreads();
    for (int k = keyBase + t; k < keyEnd; k += 256) {
        int h = hist[k - keyBase];
        off[k]  = lstBase + offs[k - keyBase];
        cntA[k] = h;
        if (csr == 0)      dis[k]  = rsqrtf((float)(h + 1));
        else if (csr == 1) Dinv[k] = h ? (1.f / (float)h) : 0.f;
        else               Binv[k] = h ? (1.f / (float)h) : 0.f;
    }
    __syncthreads();
    for (int i = t; i < cnt; i += 256) {
        unsigned u = pbuf[pstart + i];
        int lk = u >> 20;
        int slot = atomicAdd(&offs[lk], 1);
        lst[lstBase + slot] = (int)(u & 0xFFFFFu);
    }
}

// --- prep: B transposes (blocks 0-2) + fused Wlp2->btl/bias2 (block 3) -------
struct BP { const void* B; const int* fB; int K; int M; int Mp; unsigned short* out; };

__global__ void prep_k(BP p0, BP p1, BP p2,
                       const void* Wc2, const int* fWc2, const void* Wlp, const int* fWlp,
                       const void* bc2, const int* fbc2, const void* blp, const int* fblp,
                       unsigned short* __restrict__ btl, float* __restrict__ bias2, int NC) {
    int t = threadIdx.x;
    if (blockIdx.x < 3) {
        BP p = (blockIdx.x == 0) ? p0 : (blockIdx.x == 1) ? p1 : p2;
        int fb = p.fB ? p.fB[0] : 1;
        int tot = p.Mp * p.K;
        for (int e = t; e < tot; e += blockDim.x) {
            int m = e / p.K, k = e - m * p.K;
            float v = (m < p.M) ? ldf(p.B, fb, (long long)k * p.M + m) : 0.f;
            p.out[e] = f2b(v);
        }
        return;
    }
    // block 3: Wlp2 = W_c2 @ W_lp (bf16-transposed into btl), bias2
    extern __shared__ float sm[];
    float* sW2 = sm;                 // 64*NC
    float* sLP = sm + 64 * NC;       // NC*NC
    int fw2 = fWc2[0], flp = fWlp[0];
    for (int e = t; e < 64 * NC; e += blockDim.x) sW2[e] = ldf(Wc2, fw2, e);
    for (int e = t; e < NC * NC; e += blockDim.x) sLP[e] = ldf(Wlp, flp, e);
    for (int e = t; e < 48 * 64; e += blockDim.x) btl[e] = 0;   // zero-pad cols
    __syncthreads();
    for (int e = t; e < 64 * NC; e += blockDim.x) {
        int r = e / NC, c = e % NC;
        float s = 0.f;
        for (int k = 0; k < NC; k++) s = fmaf(sW2[r * NC + k], sLP[k * NC + c], s);
        btl[c * 64 + r] = f2b(s);    // transposed bf16
    }
    if (t < NC) {
        float s = ldf(blp, fblp[0], t);
        int fb2 = fbc2[0];
        for (int k = 0; k < NC; k++) s = fmaf(ldf(bc2, fb2, k), sLP[k * NC + t], s);
        bias2[t] = s;
    }
}

// --- bf16 gathers: 8 rows/wave, 8 lanes x s16x8 (16B) per row (D=64) ---------
__global__ void gat_n2e_k(const unsigned short* __restrict__ xw, const int* __restrict__ off,
                          const int* __restrict__ cnt, const int* __restrict__ lst,
                          const float* __restrict__ Binv, unsigned short* __restrict__ ef, int HE) {
    int idx = blockIdx.x * blockDim.x + threadIdx.x;
    int e = idx >> 3, l = idx & 7;
    if (e >= HE) return;
    int o = off[e], c = cnt[e];
    f32x8 a = {0.f, 0.f, 0.f, 0.f, 0.f, 0.f, 0.f, 0.f};
    int j = 0;
    for (; j + 4 <= c; j += 4) {
        int s0 = lst[o + j], s1 = lst[o + j + 1], s2 = lst[o + j + 2], s3 = lst[o + j + 3];
        f32x8 v0 = b2f8(*(const s16x8*)&xw[((long long)s0 << 6) + l * 8]);
        f32x8 v1 = b2f8(*(const s16x8*)&xw[((long long)s1 << 6) + l * 8]);
        f32x8 v2 = b2f8(*(const s16x8*)&xw[((long long)s2 << 6) + l * 8]);
        f32x8 v3 = b2f8(*(const s16x8*)&xw[((long long)s3 << 6) + l * 8]);
#pragma unroll
        for (int q = 0; q < 8; q++) a[q] += (v0[q] + v1[q]) + (v2[q] + v3[q]);
    }
    for (; j < c; j++) {
        f32x8 v = b2f8(*(const s16x8*)&xw[((long long)lst[o + j] << 6) + l * 8]);
#pragma unroll
        for (int q = 0; q < 8; q++) a[q] += v[q];
    }
    float bi = Binv[e];
#pragma unroll
    for (int q = 0; q < 8; q++) a[q] *= bi;
    *(s16x8*)&ef[((long long)e << 6) + l * 8] = f2b8(a);
}

// hyperedge -> node: out = Dinv*sum + bias (+relu), bf16 out
template <bool RELU>
__global__ void gat_e2n_k(const unsigned short* __restrict__ ef, const int* __restrict__ off,
                          const int* __restrict__ cnt, const int* __restrict__ lst,
                          const float* __restrict__ Dinv, const void* __restrict__ bias,
                          const int* __restrict__ fb, unsigned short* __restrict__ out, int N) {
    int idx = blockIdx.x * blockDim.x + threadIdx.x;
    int w = idx >> 3, l = idx & 7;
    if (w >= N) return;
    int o = off[w], c = cnt[w];
    f32x8 a = {0.f, 0.f, 0.f, 0.f, 0.f, 0.f, 0.f, 0.f};
    int j = 0;
    for (; j + 4 <= c; j += 4) {
        int s0 = lst[o + j], s1 = lst[o + j + 1], s2 = lst[o + j + 2], s3 = lst[o + j + 3];
        f32x8 v0 = b2f8(*(const s16x8*)&ef[((long long)s0 << 6) + l * 8]);
        f32x8 v1 = b2f8(*(const s16x8*)&ef[((long long)s1 << 6) + l * 8]);
        f32x8 v2 = b2f8(*(const s16x8*)&ef[((long long)s2 << 6) + l * 8]);
        f32x8 v3 = b2f8(*(const s16x8*)&ef[((long long)s3 << 6) + l * 8]);
#pragma unroll
        for (int q = 0; q < 8; q++) a[q] += (v0[q] + v1[q]) + (v2[q] + v3[q]);
    }
    for (; j < c; j++) {
        f32x8 v = b2f8(*(const s16x8*)&ef[((long long)lst[o + j] << 6) + l * 8]);
#pragma unroll
        for (int q = 0; q < 8; q++) a[q] += v[q];
    }
    float di = Dinv[w];
    int fbv = fb[0];
#pragma unroll
    for (int q = 0; q < 8; q++) {
        float bq = ldf(bias, fbv, l * 8 + q);
        a[q] = a[q] * di + bq;
        if (RELU) a[q] = fmaxf(a[q], 0.f);
    }
    *(s16x8*)&out[((long long)w << 6) + l * 8] = f2b8(a);
}

// GCN aggregation on pre-scaled bf16 y, bf16 out
template <bool RELU>
__global__ void gcn_gat_k(const unsigned short* __restrict__ y, const int* __restrict__ off,
                          const int* __restrict__ cnt, const int* __restrict__ lst,
                          const float* __restrict__ dis, const void* __restrict__ bias,
                          const int* __restrict__ fb, unsigned short* __restrict__ out, int N) {
    int idx = blockIdx.x * blockDim.x + threadIdx.x;
    int w = idx >> 3, l = idx & 7;
    if (w >= N) return;
    int o = off[w], c = cnt[w];
    f32x8 a = b2f8(*(const s16x8*)&y[((long long)w << 6) + l * 8]);
    int j = 0;
    for (; j + 4 <= c; j += 4) {
        int s0 = lst[o + j], s1 = lst[o + j + 1], s2 = lst[o + j + 2], s3 = lst[o + j + 3];
        f32x8 v0 = b2f8(*(const s16x8*)&y[((long long)s0 << 6) + l * 8]);
        f32x8 v1 = b2f8(*(const s16x8*)&y[((long long)s1 << 6) + l * 8]);
        f32x8 v2 = b2f8(*(const s16x8*)&y[((long long)s2 << 6) + l * 8]);
        f32x8 v3 = b2f8(*(const s16x8*)&y[((long long)s3 << 6) + l * 8]);
#pragma unroll
        for (int q = 0; q < 8; q++) a[q] += (v0[q] + v1[q]) + (v2[q] + v3[q]);
    }
    for (; j < c; j++) {
        f32x8 v = b2f8(*(const s16x8*)&y[((long long)lst[o + j] << 6) + l * 8]);
#pragma unroll
        for (int q = 0; q < 8; q++) a[q] += v[q];
    }
    float dd = dis[w];
    int fbv = fb[0];
#pragma unroll
    for (int q = 0; q < 8; q++) {
        float bq = ldf(bias, fbv, l * 8 + q);
        a[q] = a[q] * dd + bq;
        if (RELU) a[q] = fmaxf(a[q], 0.f);
    }
    *(s16x8*)&out[((long long)w << 6) + l * 8] = f2b8(a);
}

// final GCN aggregation over bf16 y2 (M=NC=40), writes d_out fp32.
// 5 lanes x s16x8 per row, 12 rows/wave (4 idle lanes).
__global__ void gcn_gatM_k(const unsigned short* __restrict__ y2, const int* __restrict__ off,
                           const int* __restrict__ cnt, const int* __restrict__ lst,
                           const float* __restrict__ dis, const float* __restrict__ bias2,
                           float4* __restrict__ out4, int N, int NC) {
    int idx = blockIdx.x * blockDim.x + threadIdx.x;
    int wave = idx >> 6, l64 = idx & 63;
    int lpr = NC >> 3;                 // 5
    int rpw = 64 / lpr;                // 12
    int grp = l64 / lpr, li = l64 - grp * lpr;
    int w = wave * rpw + grp;
    if (grp >= rpw || w >= N) return;
    int o = off[w], c = cnt[w];
    f32x8 a = b2f8(*(const s16x8*)&y2[(long long)w * NC + li * 8]);
    int j = 0;
    for (; j + 4 <= c; j += 4) {
        int s0 = lst[o + j], s1 = lst[o + j + 1], s2 = lst[o + j + 2], s3 = lst[o + j + 3];
        f32x8 v0 = b2f8(*(const s16x8*)&y2[(long long)s0 * NC + li * 8]);
        f32x8 v1 = b2f8(*(const s16x8*)&y2[(long long)s1 * NC + li * 8]);
        f32x8 v2 = b2f8(*(const s16x8*)&y2[(long long)s2 * NC + li * 8]);
        f32x8 v3 = b2f8(*(const s16x8*)&y2[(long long)s3 * NC + li * 8]);
#pragma unroll
        for (int q = 0; q < 8; q++) a[q] += (v0[q] + v1[q]) + (v2[q] + v3[q]);
    }
    for (; j < c; j++) {
        f32x8 v = b2f8(*(const s16x8*)&y2[(long long)lst[o + j] * NC + li * 8]);
#pragma unroll
        for (int q = 0; q < 8; q++) a[q] += v[q];
    }
    float dd = dis[w];
    const float4* b4 = (const float4*)&bias2[li * 8];
    float4 b0 = b4[0], b1 = b4[1];
    float4 lo = make_float4(a[0] * dd + b0.x, a[1] * dd + b0.y, a[2] * dd + b0.z, a[3] * dd + b0.w);
    float4 hi = make_float4(a[4] * dd + b1.x, a[5] * dd + b1.y, a[6] * dd + b1.z, a[7] * dd + b1.w);
    long long base = ((long long)w * NC + li * 8) >> 2;
    out4[base] = lo;
    out4[base + 1] = hi;
}

// --- load 8 source elements as bf16 (fp32->cvt or bf16 passthrough) ----------
__device__ __forceinline__ s16x8 load8bf(const void* A, int af, long long base) {
    s16x8 o;
    if (af) {
        float4 v0 = *(const float4*)((const float*)A + base);
        float4 v1 = *(const float4*)((const float*)A + base + 4);
        o[0] = (short)f2b(v0.x); o[1] = (short)f2b(v0.y);
        o[2] = (short)f2b(v0.z); o[3] = (short)f2b(v0.w);
        o[4] = (short)f2b(v1.x); o[5] = (short)f2b(v1.y);
        o[6] = (short)f2b(v1.z); o[7] = (short)f2b(v1.w);
    } else {
        o = *(const s16x8*)&((const unsigned short*)A)[base];
    }
    return o;
}

// --- LDS-free MFMA GEMM: one wave = 32 rows x MM cols, B^T bf16 from global --
// Fragment layouts (gfx950, verified m89/m92): A lane=row(l&15),k=8*(l>>4)+j;
// B lane=col(l&15),k=8*(l>>4)+j; D col=l&15,row=(l>>4)*4+i.
template <int KK, int MM, bool CATMODE, bool ABF16, bool SCALE>
__global__ __launch_bounds__(256)
void gemm_mfma2_k(const void* __restrict__ A, const int* __restrict__ fA,
                  const unsigned short* __restrict__ A2,
                  const unsigned short* __restrict__ Bt,
                  const float* __restrict__ dscale,
                  unsigned short* __restrict__ C, int NR) {
    constexpr int MT = (MM + 15) / 16;
    static_assert(KK % 32 == 0, "K must be multiple of 32");

    const int t = threadIdx.x;
    const int wid = t >> 6, lane = t & 63;
    const long long r0 = ((long long)blockIdx.x * 4 + wid) * 32;
    if (r0 >= NR) return;

    const int af = fA ? fA[0] : 1;
    const int arow = lane & 15;
    const int kgrp = lane >> 4;
    long long ra = r0 + arow;      if (ra > NR - 1) ra = NR - 1;
    long long rb = r0 + 16 + arow; if (rb > NR - 1) rb = NR - 1;

    f32x4 acc0[MT] = {};
    f32x4 acc1[MT] = {};
#pragma unroll
    for (int kc = 0; kc < KK; kc += 32) {
        const int kb = kc + kgrp * 8;
        s16x8 a0, a1;
        if constexpr (CATMODE) {
            if (kc < 128) {   // kb in [kc, kc+24] < 128 since kc <= 96
                a0 = load8bf(A, af, ra * 128 + kb);
                a1 = load8bf(A, af, rb * 128 + kb);
            } else {
                a0 = *(const s16x8*)&A2[ra * 64 + (kb - 128)];
                a1 = *(const s16x8*)&A2[rb * 64 + (kb - 128)];
            }
        } else if constexpr (ABF16) {
            a0 = *(const s16x8*)&((const unsigned short*)A)[ra * KK + kb];
            a1 = *(const s16x8*)&((const unsigned short*)A)[rb * KK + kb];
        } else {
            a0 = load8bf(A, af, ra * (long long)KK + kb);
            a1 = load8bf(A, af, rb * (long long)KK + kb);
        }
#pragma unroll
        for (int m = 0; m < MT; m++) {
            s16x8 b = *(const s16x8*)&Bt[(m * 16 + arow) * KK + kb];
            acc0[m] = __builtin_amdgcn_mfma_f32_16x16x32_bf16(a0, b, acc0[m], 0, 0, 0);
            acc1[m] = __builtin_amdgcn_mfma_f32_16x16x32_bf16(a1, b, acc1[m], 0, 0, 0);
        }
    }

    // ---- store: D col=lane&15, row=(lane>>4)*4+i ----
    const int col0 = lane & 15;
    const int rsub = (lane >> 4) * 4;
#pragma unroll
    for (int h = 0; h < 2; h++) {
#pragma unroll
        for (int i = 0; i < 4; i++) {
            long long r = r0 + h * 16 + rsub + i;
            if (r < NR) {
                float s = SCALE ? dscale[r] : 1.f;
#pragma unroll
                for (int m = 0; m < MT; m++) {
                    int col = m * 16 + col0;
                    float val = h ? acc1[m][i] : acc0[m][i];
                    if (MT * 16 == MM || col < MM)
                        C[r * MM + col] = f2b(val * s);
                }
            }
        }
    }
}

static inline dim3 g1d(long long n, int b) { return dim3((unsigned)((n + b - 1) / b)); }
static inline int imin(int a, int b) { return a < b ? a : b; }

extern "C" void kernel_launch(void* const* d_in, const int* in_sizes, int n_in,
                              void* d_out, int out_size, void* d_ws, size_t ws_size,
                              hipStream_t stream) {
    const int N  = in_sizes[0] / 128;   // 100000
    const int E  = in_sizes[1] / 2;     // 1600000
    const int P  = in_sizes[2] / 2;     // 800000
    const int HE = 20000;
    const int NC = in_sizes[9] / 64;    // 40

    const void* x    = d_in[0];
    const int*  ew   = (const int*)d_in[1];
    const int*  hw   = (const int*)d_in[2];
    const void* W_h1 = d_in[3];
    const void* b_h1 = d_in[4];
    const void* W_h2 = d_in[5];
    const void* b_h2 = d_in[6];
    const void* W_c1 = d_in[7];
    const void* b_c1 = d_in[8];
    const void* W_c2 = d_in[9];
    const void* b_c2 = d_in[10];
    const void* W_lp = d_in[11];
    const void* b_lp = d_in[12];

    int shN = 0; while (((N - 1) >> shN) >= 256) shN++;   // 9
    int shH = 0; while (((HE - 1) >> shH) >= 256) shH++;  // 7

    long long T = (long long)E + P;
    int nChunks = (int)((T + PCHUNK - 1) / PCHUNK);

    // ---- workspace ----
    char* wp = (char*)d_ws;
    auto allocF = [&](size_t n) { float* p = (float*)wp; wp += n * 4; return p; };
    auto allocI = [&](size_t n) { int* p = (int*)wp; wp += n * 4; return p; };
    unsigned short* ub  = (unsigned short*)allocF((size_t)N * 32);   // bf16 N*64 (GEMM out)
    unsigned short* hb  = (unsigned short*)allocF((size_t)N * 32);   // bf16 N*64 (gather out)
    unsigned short* efb = (unsigned short*)allocF((size_t)HE * 32);  // bf16 HE*64
    float* dis   = allocF(N);
    float* Dinv  = allocF(N);
    float* Binv  = allocF(HE);
    float* bias2 = allocF(NC);
    unsigned short* bt1 = (unsigned short*)allocF((size_t)64 * 128 / 2);  // W_h1^T bf16
    unsigned short* bt2 = (unsigned short*)allocF((size_t)64 * 64 / 2);   // W_h2^T bf16
    unsigned short* btc = (unsigned short*)allocF((size_t)64 * 192 / 2);  // W_c1^T bf16
    unsigned short* btl = (unsigned short*)allocF((size_t)48 * 64 / 2);   // Wlp2^T bf16
    int* ecnt  = allocI(N);
    int* pcntN = allocI(N);
    int* pcntH = allocI(HE);
    int* eoff  = allocI(N);
    int* poffN = allocI(N);
    int* poffH = allocI(HE);
    int* esrc  = allocI(E);
    int* pheL  = allocI(P);
    int* pniL  = allocI(P);
    int* gBkt  = allocI(768);
    int* bkOff = allocI(768);
    int* gcur  = allocI(768);
    int* FL    = allocI(16);
    int* chunkHist = allocI((size_t)nChunks * 768);
    unsigned* pbuf = (unsigned*)allocI((size_t)E + 2 * (size_t)P);

    dim3 b256(256), b1024(PTHREADS), d1(1);

    // ---- dtype detection ----
    DPtrs dp;
    const void* farr[11] = {x, W_h1, b_h1, W_h2, b_h2, W_c1, b_c1, W_c2, b_c2, W_lp, b_lp};
    const int   fsz[11]  = {in_sizes[0], in_sizes[3], in_sizes[4], in_sizes[5], in_sizes[6],
                            in_sizes[7], in_sizes[8], in_sizes[9], in_sizes[10], in_sizes[11],
                            in_sizes[12]};
    for (int i = 0; i < 11; ++i) { dp.p[i] = farr[i]; dp.n[i] = fsz[i]; }
    dp.p[11] = ew; dp.n[11] = imin(E, 1024);
    dp.p[12] = hw; dp.n[12] = imin(P, 1024);
    detect_k<<<dim3(13), b256, 0, stream>>>(dp, FL);
    const int* fX   = FL + 0;
    const int* fWh1 = FL + 1,  *fbh1 = FL + 2;
    const int* fWh2 = FL + 3,  *fbh2 = FL + 4;
    const int* fWc1 = FL + 5,  *fbc1 = FL + 6;
    const int* fWc2 = FL + 7,  *fbc2 = FL + 8;
    const int* fWlp = FL + 9,  *fblp = FL + 10;

    // ---- prep (B transposes + fused tail weights) ----
    {
        BP p0 = {W_h1, fWh1, 128, 64, 64, bt1};
        BP p1 = {W_h2, fWh2,  64, 64, 64, bt2};
        BP p2 = {W_c1, fWc1, 192, 64, 64, btc};
        prep_k<<<dim3(4), b256, (64 * NC + NC * NC) * 4, stream>>>(
            p0, p1, p2, W_c2, fWc2, W_lp, fWlp, b_c2, fbc2, b_lp, fblp, btl, bias2, NC);
    }

    // ---- CSR build ----
    hipMemsetAsync(gBkt, 0, 768 * 4, stream);
    chunkhist_k<<<dim3(nChunks), b1024, 0, stream>>>(ew, hw, FL, gBkt, chunkHist,
                                                     E, P, N, HE, shN, shH);
    bucket_scan_k<<<d1, b256, 0, stream>>>(gBkt, bkOff, gcur, E, P);
    place_k<<<dim3(nChunks), b1024, 0, stream>>>(ew, hw, FL, gcur, chunkHist, pbuf,
                                                 E, P, N, HE, shN, shH);
    build_k<<<dim3(768), b256, 0, stream>>>(pbuf, gBkt, bkOff,
                                            eoff, ecnt, esrc,
                                            poffN, pcntN, pheL,
                                            poffH, pcntH, pniL,
                                            dis, Dinv, Binv,
                                            E, P, N, HE, shN, shH);

    const dim3 mfmaGrid((N + 127) / 128);
    const dim3 gatN8(g1d((long long)N * 8, 256));
    const dim3 gatH8(g1d((long long)HE * 8, 256));
    const int rpw = 64 / (NC >> 3);   // 12
    const dim3 gatNC(g1d((long long)((N + rpw - 1) / rpw) * 64, 256));

    // ---- hyperconv 1 ----
    gemm_mfma2_k<128, 64, false, false, false><<<mfmaGrid, b256, 0, stream>>>(
        x, fX, nullptr, bt1, nullptr, ub, N);
    gat_n2e_k<<<gatH8, b256, 0, stream>>>(ub, poffH, pcntH, pniL, Binv, efb, HE);
    gat_e2n_k<true><<<gatN8, b256, 0, stream>>>(efb, poffN, pcntN, pheL, Dinv, b_h1, fbh1, hb, N);

    // ---- hyperconv 2 ----
    gemm_mfma2_k<64, 64, false, true, false><<<mfmaGrid, b256, 0, stream>>>(
        hb, nullptr, nullptr, bt2, nullptr, ub, N);
    gat_n2e_k<<<gatH8, b256, 0, stream>>>(ub, poffH, pcntH, pniL, Binv, efb, HE);
    gat_e2n_k<false><<<gatN8, b256, 0, stream>>>(efb, poffN, pcntN, pheL, Dinv, b_h2, fbh2, hb, N);
    // hb = x_hyper (bf16)

    // ---- gcn 1: y = ([x|x_hyper] @ W_c1) * dis (bf16), then gather ----
    gemm_mfma2_k<192, 64, true, false, true><<<mfmaGrid, b256, 0, stream>>>(
        x, fX, hb, btc, dis, ub, N);
    gcn_gat_k<true><<<gatN8, b256, 0, stream>>>(ub, eoff, ecnt, esrc, dis, b_c1, fbc1, hb, N);

    // ---- gcn 2 + final linear fused: y2 = (hb @ Wlp2) * dis (bf16), gather ----
    gemm_mfma2_k<64, 40, false, true, true><<<mfmaGrid, b256, 0, stream>>>(
        hb, nullptr, nullptr, btl, dis, ub, N);
    gcn_gatM_k<<<gatNC, b256, 0, stream>>>(ub, eoff, ecnt, esrc, dis, bias2, (float4*)d_out, N, NC);
}